// Round 1
// baseline (5288.057 us; speedup 1.0000x reference)
//
#include <hip/hip_runtime.h>

// ---------------------------------------------------------------------------
// Dims
// ---------------------------------------------------------------------------
// B=512 A=256 CIN=7 CC=16 D=48 H=8 DH=6 E=512 S=32 T=32 NL=4 STOT=64
// CONV_IN=4096 HID=8192 ENC=1536 DEC_HID=3072 DEC_OUT=1792
static const double SCALE_ = 6.928203230275509;  // sqrt(48)

__device__ inline float  fma_t(float a, float b, float c)  { return fmaf(a, b, c); }
__device__ inline double fma_t(double a, double b, double c){ return fma(a, b, c); }

// ---------------------------------------------------------------------------
// Helpers
// ---------------------------------------------------------------------------
// noinline dual-acc dot (prefill; pairing matches R3 exactly)
__device__ __attribute__((noinline)) double dotW(const double* a,
                                                 const float* W, int n, int ldw,
                                                 double init) {
  double a0 = init, a1 = 0.0;
#pragma unroll 2
  for (int i = 0; i < n; i += 2) {
    a0 = fma(a[i],     (double)W[i * ldw],       a0);
    a1 = fma(a[i + 1], (double)W[(i + 1) * ldw], a1);
  }
  return a0 + a1;
}

// quad-acc dots over a contiguous (pre-transposed) weight row.
// Accumulator pairing (i%4 -> c0..c3) identical to the old dotN<N> -> outputs
// are bit-identical to the previous passing kernel.
__device__ __forceinline__ double dot48_row(const double* a, const float* Wrow, double init) {
  double c0 = init, c1 = 0.0, c2 = 0.0, c3 = 0.0;
#pragma unroll
  for (int i = 0; i < 48; i += 4) {
    const float4 wv = *(const float4*)(Wrow + i);
    c0 = fma(a[i],     (double)wv.x, c0);
    c1 = fma(a[i + 1], (double)wv.y, c1);
    c2 = fma(a[i + 2], (double)wv.z, c2);
    c3 = fma(a[i + 3], (double)wv.w, c3);
  }
  return (c0 + c1) + (c2 + c3);
}

__device__ __forceinline__ double dot96_row(const double* a, const float* Wrow, double init) {
  double c0 = init, c1 = 0.0, c2 = 0.0, c3 = 0.0;
#pragma unroll
  for (int i = 0; i < 96; i += 4) {
    const float4 wv = *(const float4*)(Wrow + i);
    c0 = fma(a[i],     (double)wv.x, c0);
    c1 = fma(a[i + 1], (double)wv.y, c1);
    c2 = fma(a[i + 2], (double)wv.z, c2);
    c3 = fma(a[i + 3], (double)wv.w, c3);
  }
  return (c0 + c1) + (c2 + c3);
}

// LayerNorm stats over 48 elements (redundant per-thread; identical to prev)
__device__ __attribute__((noinline)) double2 ln_stats48(const double* x) {
  double s0 = 0, s1 = 0, q0 = 0, q1 = 0;
#pragma unroll 2
  for (int i = 0; i < 48; i += 2) {
    const double va = x[i], vb = x[i + 1];
    s0 += va; q0 = fma(va, va, q0);
    s1 += vb; q1 = fma(vb, vb, q1);
  }
  const double m = (s0 + s1) / 48.0;
  const double rs = 1.0 / sqrt((q0 + q1) / 48.0 - m * m + 1e-5);
  return make_double2(m, rs);
}

__device__ __attribute__((noinline)) double exp_ni(double x) { return exp(x); }

// ---------------------------------------------------------------------------
// K1: BatchNorm partial sums (deterministic, fp64)
// ---------------------------------------------------------------------------
__global__ __launch_bounds__(256) void bn_partial_kernel(const float* __restrict__ x,
                                                         double* __restrict__ part) {
  __shared__ double sh[256 * 14];
  const int tid = threadIdx.x;
  const int idx = blockIdx.x * 256 + tid;  // (b,a) pair, 0..131071
  const float* p = x + (size_t)idx * 7;
  for (int c = 0; c < 7; ++c) {
    double v = (double)p[c];
    sh[tid * 14 + c] = v;
    sh[tid * 14 + 7 + c] = v * v;
  }
  __syncthreads();
  if (tid < 14) {
    double acc = 0.0;
    for (int t = 0; t < 256; ++t) acc += sh[t * 14 + tid];
    part[blockIdx.x * 14 + tid] = acc;
  }
}

// K2: finalize BN stats -> per-channel scale/shift (fp64)
__global__ void bn_final_kernel(const double* __restrict__ part,
                                const float* __restrict__ g, const float* __restrict__ bb,
                                double* __restrict__ stat) {
  const int c = threadIdx.x;
  if (c < 7) {
    double s = 0.0, s2 = 0.0;
    for (int i = 0; i < 512; ++i) { s += part[i * 14 + c]; s2 += part[i * 14 + 7 + c]; }
    const double mean = s / 131072.0;
    const double var = s2 / 131072.0 - mean * mean;
    const double rstd = 1.0 / sqrt(var + 1e-5);
    const double scale = rstd * (double)g[c];
    stat[c] = scale;                          // x*scale + shift
    stat[7 + c] = (double)bb[c] - mean * scale;
  }
}

// ---------------------------------------------------------------------------
// K3: BN-apply + Conv1d(7->16,k=5,pad=2) + flatten -> xf [512, 16*256] fp64
// ---------------------------------------------------------------------------
__global__ __launch_bounds__(256) void conv_kernel(const float* __restrict__ x,
                                                   const float* __restrict__ wconv,
                                                   const float* __restrict__ cb,
                                                   const double* __restrict__ stat,
                                                   double* __restrict__ xf) {
  __shared__ double wsh[560 + 14];
  const int tid = threadIdx.x;
  for (int i = tid; i < 560; i += 256) wsh[i] = (double)wconv[i];
  for (int i = tid; i < 14; i += 256) wsh[560 + i] = stat[i];
  __syncthreads();
  const int idx = blockIdx.x * 256 + tid;    // b*4096 + o*256 + a
  const int a = idx & 255;
  const int o = (idx >> 8) & 15;
  const int b = idx >> 12;
  double acc = (double)cb[o];
  const float* xb = x + (size_t)b * (256 * 7);
  for (int k = 0; k < 5; ++k) {
    const int pos = a + k - 2;
    if (pos < 0 || pos >= 256) continue;
    const float* xp = xb + pos * 7;
    for (int ci = 0; ci < 7; ++ci) {
      const double xn = (double)xp[ci] * wsh[560 + ci] + wsh[567 + ci];
      acc = fma(xn, wsh[(o * 7 + ci) * 5 + k], acc);
    }
  }
  xf[idx] = acc;
}

// ---------------------------------------------------------------------------
// fp64 GEMM, 128x64 tile, BK=16, 256 threads, 8x4 microtile. (unchanged)
// ---------------------------------------------------------------------------
template <typename T, bool BIAS, bool RELU>
__global__ __launch_bounds__(256) void gemm128_kernel(const T* __restrict__ A,
                                                      const float* __restrict__ Bm,
                                                      const float* __restrict__ bias,
                                                      T* __restrict__ C,
                                                      const int M, const int N, const int K,
                                                      const int kc) {
  __shared__ T As[16][130];  // [k][m], pad +2
  __shared__ T Bs[16][66];   // [k][n], pad +2
  const int tid = threadIdx.x;
  const int tx = tid & 15, ty = tid >> 4;
  const int n0 = blockIdx.x * 64, m0 = blockIdx.y * 128;
  const int k0 = blockIdx.z * kc, kend = k0 + kc;
  const int ar = tid >> 1, ac = (tid & 1) * 8;   // A: 128 rows x 16 k
  const int br = tid >> 4, bc = (tid & 15) * 4;  // B: 16 k x 64 n
  const T* Ap = A + (size_t)(m0 + ar) * K;
  const float* Bp = Bm + (size_t)br * N + n0 + bc;
  T acc[8][4] = {};
  for (int k = k0; k < kend; k += 16) {
    T av8[8];
#pragma unroll
    for (int i = 0; i < 8; ++i) av8[i] = Ap[k + ac + i];
    const float4 bw = *(const float4*)(Bp + (size_t)k * N);
#pragma unroll
    for (int i = 0; i < 8; ++i) As[ac + i][ar] = av8[i];
    Bs[br][bc] = (T)bw.x; Bs[br][bc + 1] = (T)bw.y;
    Bs[br][bc + 2] = (T)bw.z; Bs[br][bc + 3] = (T)bw.w;
    __syncthreads();
#pragma unroll
    for (int kk = 0; kk < 16; ++kk) {
      T a[8], b[4];
#pragma unroll
      for (int i = 0; i < 8; ++i) a[i] = As[kk][ty * 8 + i];
#pragma unroll
      for (int j = 0; j < 4; ++j) b[j] = Bs[kk][tx * 4 + j];
#pragma unroll
      for (int i = 0; i < 8; ++i)
#pragma unroll
        for (int j = 0; j < 4; ++j) acc[i][j] = fma_t(a[i], b[j], acc[i][j]);
    }
    __syncthreads();
  }
  T* Cp = C + (size_t)blockIdx.z * M * N;
#pragma unroll
  for (int i = 0; i < 8; ++i) {
    const int row = m0 + ty * 8 + i;
#pragma unroll
    for (int j = 0; j < 4; ++j) {
      const int col = n0 + tx * 4 + j;
      T v = acc[i][j];
      if (BIAS) v += (T)bias[col];
      if (RELU) v = v > (T)0 ? v : (T)0;
      Cp[(size_t)row * N + col] = v;
    }
  }
}

// Old 64x64 fp32 GEMM (decoder)
template <typename T, bool BIAS, bool RELU>
__global__ __launch_bounds__(256) void gemm_kernel(const T* __restrict__ A,
                                                   const float* __restrict__ Bm,
                                                   const float* __restrict__ bias,
                                                   T* __restrict__ C,
                                                   const int M, const int N, const int K,
                                                   const int kc) {
  __shared__ T As[16][65];
  __shared__ T Bs[16][65];
  const int tid = threadIdx.x;
  const int tx = tid & 15, ty = tid >> 4;
  const int n0 = blockIdx.x * 64, m0 = blockIdx.y * 64;
  const int k0 = blockIdx.z * kc, kend = k0 + kc;
  const int ar = tid >> 2, ac = (tid & 3) * 4;
  const int br = tid >> 4, bc = (tid & 15) * 4;
  const T* Ap = A + (size_t)(m0 + ar) * K;
  const float* Bp = Bm + (size_t)br * N + n0 + bc;
  T acc[4][4] = {};
  for (int k = k0; k < kend; k += 16) {
    const T a0 = Ap[k + ac], a1 = Ap[k + ac + 1], a2 = Ap[k + ac + 2], a3 = Ap[k + ac + 3];
    const float4 bw = *(const float4*)(Bp + (size_t)k * N);
    As[ac][ar] = a0; As[ac + 1][ar] = a1; As[ac + 2][ar] = a2; As[ac + 3][ar] = a3;
    Bs[br][bc] = (T)bw.x; Bs[br][bc + 1] = (T)bw.y; Bs[br][bc + 2] = (T)bw.z; Bs[br][bc + 3] = (T)bw.w;
    __syncthreads();
#pragma unroll
    for (int kk = 0; kk < 16; ++kk) {
      T av[4], bv2[4];
#pragma unroll
      for (int i = 0; i < 4; ++i) av[i] = As[kk][ty * 4 + i];
#pragma unroll
      for (int j = 0; j < 4; ++j) bv2[j] = Bs[kk][tx * 4 + j];
#pragma unroll
      for (int i = 0; i < 4; ++i)
#pragma unroll
        for (int j = 0; j < 4; ++j) acc[i][j] = fma_t(av[i], bv2[j], acc[i][j]);
    }
    __syncthreads();
  }
  T* Cp = C + (size_t)blockIdx.z * M * N;
#pragma unroll
  for (int i = 0; i < 4; ++i) {
    const int row = m0 + ty * 4 + i;
#pragma unroll
    for (int j = 0; j < 4; ++j) {
      const int col = n0 + tx * 4 + j;
      T v = acc[i][j];
      if (BIAS) v += (T)bias[col];
      if (RELU) v = v > (T)0 ? v : (T)0;
      Cp[(size_t)row * N + col] = v;
    }
  }
}

// split-K=2 reduction + bias (fp64, deterministic)
__global__ __launch_bounds__(256) void reduce2_bias_kernel(const double* __restrict__ part,
                                                           const float* __restrict__ bias,
                                                           double* __restrict__ out,
                                                           const int MN, const int N) {
  const int i = blockIdx.x * 256 + threadIdx.x;
  if (i < MN) out[i] = part[i] + part[MN + i] + (double)bias[i % N];
}

// ---------------------------------------------------------------------------
// K4b: pre-transpose weights so each output's weight row is contiguous.
// WqT/WkT/WvT/WoT: [4][48][48] (T[l][j][i] = W[l][i][j])
// W1T: [4][96][48], W2T: [4][48][96], embT: [512][48]
// ---------------------------------------------------------------------------
__global__ __launch_bounds__(256) void transpose_weights_kernel(
    const float* __restrict__ Wq, const float* __restrict__ Wk,
    const float* __restrict__ Wv, const float* __restrict__ Wo,
    const float* __restrict__ W1, const float* __restrict__ W2,
    const float* __restrict__ emb,
    float* __restrict__ WqT, float* __restrict__ WkT,
    float* __restrict__ WvT, float* __restrict__ WoT,
    float* __restrict__ W1T, float* __restrict__ W2T,
    float* __restrict__ embT) {
  const int t = blockIdx.x * 256 + threadIdx.x;  // 0 .. 98303
  if (t < 36864) {                     // Wq|Wk|Wv|Wo: 4 arrays x 4 layers x 48x48
    const int a = t / 9216, r = t - a * 9216;
    const int l = r / 2304, e = r - l * 2304;
    const int i = e / 48, j = e - i * 48;
    const float* src = a == 0 ? Wq : a == 1 ? Wk : a == 2 ? Wv : Wo;
    float* dst = a == 0 ? WqT : a == 1 ? WkT : a == 2 ? WvT : WoT;
    dst[l * 2304 + j * 48 + i] = src[l * 2304 + i * 48 + j];
  } else if (t < 55296) {              // W1 [4][48][96] -> W1T [4][96][48]
    const int t1 = t - 36864;
    const int l = t1 / 4608, e = t1 - l * 4608;
    const int i = e / 96, j = e - i * 96;
    W1T[l * 4608 + j * 48 + i] = W1[l * 4608 + i * 96 + j];
  } else if (t < 73728) {              // W2 [4][96][48] -> W2T [4][48][96]
    const int t2 = t - 55296;
    const int l = t2 / 4608, e = t2 - l * 4608;
    const int i = e / 48, j = e - i * 48;
    W2T[l * 4608 + j * 96 + i] = W2[l * 4608 + i * 48 + j];
  } else {                             // emb [48][512] -> embT [512][48]
    const int t3 = t - 73728;
    const int d = t3 / 512, e = t3 - d * 512;
    embT[e * 48 + d] = emb[d * 512 + e];
  }
}

// ---------------------------------------------------------------------------
// K5: prefill — one block per batch element (unchanged; bit-identical)
// ---------------------------------------------------------------------------
__global__ __launch_bounds__(256) void prefill_kernel(
    const double* __restrict__ toks,
    const float* __restrict__ lnq_g, const float* __restrict__ lnq_b,
    const float* __restrict__ Wq, const float* __restrict__ bq,
    const float* __restrict__ lnk_g, const float* __restrict__ lnk_b,
    const float* __restrict__ Wk, const float* __restrict__ bk,
    const float* __restrict__ lnv_g, const float* __restrict__ lnv_b,
    const float* __restrict__ Wv, const float* __restrict__ bvv,
    const float* __restrict__ Wo, const float* __restrict__ bo,
    const float* __restrict__ mln_g, const float* __restrict__ mln_b,
    const float* __restrict__ W1, const float* __restrict__ b1,
    const float* __restrict__ W2, const float* __restrict__ b2,
    double* __restrict__ kcache, double* __restrict__ vcache) {
  const int b = blockIdx.x, tid = threadIdx.x;
  __shared__ double xcur[1536], abuf[1536], qbuf[1536], kvbuf[3072];
  __shared__ double mean[32], rstd[32];
  double* kb = kvbuf;
  double* vb = kvbuf + 1536;

#pragma unroll 1
  for (int i = tid; i < 1536; i += 256) xcur[i] = toks[(size_t)b * 1536 + i];
  __syncthreads();

#pragma unroll 1
  for (int l = 0; l < 4; ++l) {
    if (tid < 32) {
      double s = 0.0, s2 = 0.0;
#pragma unroll 4
      for (int i = 0; i < 48; ++i) { const double v = xcur[tid * 48 + i]; s += v; s2 += v * v; }
      const double m = s / 48.0;
      mean[tid] = m;
      rstd[tid] = 1.0 / sqrt(s2 / 48.0 - m * m + 1e-5);
    }
    __syncthreads();
    const bool last = (l == 3);

    if (!last) {  // q projection
#pragma unroll 1
      for (int i = tid; i < 1536; i += 256) {
        const int t = i / 48, d = i % 48;
        abuf[i] = (xcur[i] - mean[t]) * rstd[t] * (double)lnq_g[l * 48 + d] + (double)lnq_b[l * 48 + d];
      }
      __syncthreads();
#pragma unroll 1
      for (int i = tid; i < 1536; i += 256) {
        const int t = i / 48, j = i % 48;
        qbuf[i] = dotW(abuf + t * 48, Wq + l * 2304 + j, 48, 48, (double)bq[l * 48 + j]);
      }
      __syncthreads();
    }
    // k projection
#pragma unroll 1
    for (int i = tid; i < 1536; i += 256) {
      const int t = i / 48, d = i % 48;
      abuf[i] = (xcur[i] - mean[t]) * rstd[t] * (double)lnk_g[l * 48 + d] + (double)lnk_b[l * 48 + d];
    }
    __syncthreads();
#pragma unroll 1
    for (int i = tid; i < 1536; i += 256) {
      const int t = i / 48, j = i % 48;
      kb[i] = dotW(abuf + t * 48, Wk + l * 2304 + j, 48, 48, (double)bk[l * 48 + j]);
    }
    __syncthreads();
    // v projection
#pragma unroll 1
    for (int i = tid; i < 1536; i += 256) {
      const int t = i / 48, d = i % 48;
      abuf[i] = (xcur[i] - mean[t]) * rstd[t] * (double)lnv_g[l * 48 + d] + (double)lnv_b[l * 48 + d];
    }
    __syncthreads();
#pragma unroll 1
    for (int i = tid; i < 1536; i += 256) {
      const int t = i / 48, j = i % 48;
      vb[i] = dotW(abuf + t * 48, Wv + l * 2304 + j, 48, 48, (double)bvv[l * 48 + j]);
    }
    __syncthreads();
    // store k,v to cache at pos t
#pragma unroll 1
    for (int i = tid; i < 1536; i += 256) {
      const int t = i / 48, j = i % 48;
      const int h = j / 6, d = j % 6;
      const size_t ci = ((((size_t)b * 4 + l) * 8 + h) * 64 + t) * 6 + d;
      kcache[ci] = kb[i];
      vcache[ci] = vb[i];
    }

    if (!last) {
      // attention: thread = (token t, head h). mask only (t=0, j=31).
      const int t = tid >> 3, h = tid & 7;
      const double* qp = qbuf + t * 48 + h * 6;
      const double q0 = qp[0], q1 = qp[1], q2 = qp[2], q3 = qp[3], q4 = qp[4], q5 = qp[5];
      double mx = -1e300;
#pragma unroll 4
      for (int j = 0; j < 32; ++j) {
        const double* kp = kb + j * 48 + h * 6;
        double sv = q0 * kp[0];
        sv = fma(q1, kp[1], sv); sv = fma(q2, kp[2], sv); sv = fma(q3, kp[3], sv);
        sv = fma(q4, kp[4], sv); sv = fma(q5, kp[5], sv);
        sv /= SCALE_;
        if (t == 0 && j == 31) sv -= 999.0;
        mx = sv > mx ? sv : mx;
      }
      double den = 0, o0 = 0, o1 = 0, o2 = 0, o3 = 0, o4 = 0, o5 = 0;
#pragma unroll 4
      for (int j = 0; j < 32; ++j) {
        const double* kp = kb + j * 48 + h * 6;
        double sv = q0 * kp[0];
        sv = fma(q1, kp[1], sv); sv = fma(q2, kp[2], sv); sv = fma(q3, kp[3], sv);
        sv = fma(q4, kp[4], sv); sv = fma(q5, kp[5], sv);
        sv /= SCALE_;
        if (t == 0 && j == 31) sv -= 999.0;
        const double e = exp_ni(sv - mx);
        den += e;
        const double* vp = vb + j * 48 + h * 6;
        o0 = fma(e, vp[0], o0); o1 = fma(e, vp[1], o1); o2 = fma(e, vp[2], o2);
        o3 = fma(e, vp[3], o3); o4 = fma(e, vp[4], o4); o5 = fma(e, vp[5], o5);
      }
      abuf[t * 48 + h * 6 + 0] = o0 / den;
      abuf[t * 48 + h * 6 + 1] = o1 / den;
      abuf[t * 48 + h * 6 + 2] = o2 / den;
      abuf[t * 48 + h * 6 + 3] = o3 / den;
      abuf[t * 48 + h * 6 + 4] = o4 / den;
      abuf[t * 48 + h * 6 + 5] = o5 / den;
      __syncthreads();
      // Wo + residual
#pragma unroll 1
      for (int i = tid; i < 1536; i += 256) {
        const int t2 = i / 48, j = i % 48;
        xcur[i] += dotW(abuf + t2 * 48, Wo + l * 2304 + j, 48, 48, (double)bo[l * 48 + j]);
      }
      __syncthreads();
      // MLP LN
      if (tid < 32) {
        double s = 0.0, s2 = 0.0;
#pragma unroll 4
        for (int i = 0; i < 48; ++i) { const double v = xcur[tid * 48 + i]; s += v; s2 += v * v; }
        const double m = s / 48.0;
        mean[tid] = m;
        rstd[tid] = 1.0 / sqrt(s2 / 48.0 - m * m + 1e-5);
      }
      __syncthreads();
#pragma unroll 1
      for (int i = tid; i < 1536; i += 256) {
        const int t2 = i / 48, d = i % 48;
        qbuf[i] = (xcur[i] - mean[t2]) * rstd[t2] * (double)mln_g[l * 48 + d] + (double)mln_b[l * 48 + d];
      }
      __syncthreads();
#pragma unroll 1
      for (int i = tid; i < 3072; i += 256) {
        const int t2 = i / 96, jj = i % 96;
        const double acc = dotW(qbuf + t2 * 48, W1 + l * 4608 + jj, 48, 96, (double)b1[l * 96 + jj]);
        kvbuf[i] = acc > 0 ? acc : 0;
      }
      __syncthreads();
#pragma unroll 1
      for (int i = tid; i < 1536; i += 256) {
        const int t2 = i / 48, j = i % 48;
        abuf[i] = dotW(kvbuf + t2 * 96, W2 + l * 4608 + j, 96, 48, (double)b2[l * 48 + j]);
      }
      __syncthreads();
#pragma unroll 1
      for (int i = tid; i < 1536; i += 256) xcur[i] = abuf[i];
      __syncthreads();
    }
  }
}

// ---------------------------------------------------------------------------
// K6: autoregressive loop — ONE WAVE (64 threads) per batch element.
//   - no inter-wave barriers; compiler can overlap global loads with compute
//   - weights read directly from pre-transposed global copies (contiguous rows)
//   - LN params + biases preloaded to LDS once
//   - sampling fully register-resident (bit-identical index to prev kernel)
// ---------------------------------------------------------------------------
__global__ __launch_bounds__(64, 1) void ar_kernel(
    const float* __restrict__ pos_enc, const float* __restrict__ u,
    const float* __restrict__ lnq_g, const float* __restrict__ lnq_b,
    const float* __restrict__ WqT, const float* __restrict__ bq,
    const float* __restrict__ lnk_g, const float* __restrict__ lnk_b,
    const float* __restrict__ WkT, const float* __restrict__ bk,
    const float* __restrict__ lnv_g, const float* __restrict__ lnv_b,
    const float* __restrict__ WvT, const float* __restrict__ bvv,
    const float* __restrict__ WoT, const float* __restrict__ bo,
    const float* __restrict__ mln_g, const float* __restrict__ mln_b,
    const float* __restrict__ W1T, const float* __restrict__ b1,
    const float* __restrict__ W2T, const float* __restrict__ b2,
    const float* __restrict__ embT,
    double* __restrict__ kcache, double* __restrict__ vcache,
    float* __restrict__ out_tok) {
  const int b = blockIdx.x, tid = threadIdx.x;  // 64 threads = 1 wave
  __shared__ double xtk[48], anorm[144], qs[48], os[48], hh[96];
  // par layout (floats):
  //    0 lnq_g |  192 lnq_b |  384 lnk_g |  576 lnk_b |  768 lnv_g |  960 lnv_b
  // 1152 mln_g | 1344 mln_b | 1536 bq | 1728 bk | 1920 bv | 2112 bo
  // 2304 b1[384] | 2688 b2[192]   -> total 2880
  __shared__ float par[2880];
  {
    const float* srcs[14] = {lnq_g, lnq_b, lnk_g, lnk_b, lnv_g, lnv_b, mln_g, mln_b,
                             bq, bk, bvv, bo, b1, b2};
    const int sz[14] = {192, 192, 192, 192, 192, 192, 192, 192, 192, 192, 192, 192, 384, 192};
    int base = 0;
#pragma unroll 1
    for (int a2 = 0; a2 < 14; ++a2) {
      for (int i = tid; i < sz[a2]; i += 64) par[base + i] = srcs[a2][i];
      base += sz[a2];
    }
  }
  __syncthreads();

#pragma unroll 1
  for (int step = 0; step < 32; ++step) {
    const int p = 32 + step;
    if (tid < 48) xtk[tid] = (double)pos_enc[step * 48 + tid];
    __syncthreads();

#pragma unroll 1
    for (int l = 0; l < 4; ++l) {
      // ---- LN1 (redundant stats, all 64 lanes) + 3 norms (144 outputs) ----
      {
        const double2 st = ln_stats48(xtk);
#pragma unroll
        for (int i = tid; i < 144; i += 64) {
          const int which = i / 48, d = i - which * 48;
          const float* gp = par + 384 * which;   // lnq_g / lnk_g / lnv_g
          const float* bp = gp + 192;
          anorm[i] = (xtk[d] - st.x) * st.y * (double)gp[l * 48 + d] + (double)bp[l * 48 + d];
        }
      }
      __syncthreads();
      // ---- q,k,v projections (direct transposed-weight reads) ----
#pragma unroll
      for (int i = tid; i < 144; i += 64) {
        const int which = i / 48, j = i - which * 48;
        const float* WT = which == 0 ? WqT : which == 1 ? WkT : WvT;
        const float* bbp = par + 1536 + 192 * which;  // bq / bk / bv
        const double acc = dot48_row(anorm + which * 48, WT + l * 2304 + j * 48,
                                     (double)bbp[l * 48 + j]);
        if (which == 0) {
          qs[j] = acc;
        } else {
          const int h = j / 6, d = j - h * 6;
          const size_t ci = ((((size_t)b * 4 + l) * 8 + h) * 64 + p) * 6 + d;
          if (which == 1) kcache[ci] = acc; else vcache[ci] = acc;
        }
      }
      __syncthreads();
      // ---- attention over [0,p): 8 lanes per head, <=8 keys per lane ----
      {
        const int h = tid >> 3, rl = tid & 7;
        const double* kcb = kcache + ((((size_t)b * 4 + l) * 8 + h) * 64) * 6;
        const double* vcb = vcache + ((((size_t)b * 4 + l) * 8 + h) * 64) * 6;
        double qv[6];
#pragma unroll
        for (int d = 0; d < 6; ++d) qv[d] = qs[h * 6 + d];
        double sv[8];
        double mx = -1e300;
        int nk = 0;
#pragma unroll 2
        for (int r = rl; r < p; r += 8) {
          const double* kp = kcb + r * 6;
          double s = qv[0] * kp[0];
          s = fma(qv[1], kp[1], s); s = fma(qv[2], kp[2], s); s = fma(qv[3], kp[3], s);
          s = fma(qv[4], kp[4], s); s = fma(qv[5], kp[5], s);
          s /= SCALE_;
          sv[nk++] = s;
          mx = s > mx ? s : mx;
        }
#pragma unroll
        for (int off = 1; off < 8; off <<= 1) {
          const double o2 = __shfl_xor(mx, off); mx = o2 > mx ? o2 : mx;
        }
        double den = 0.0, o[6] = {0, 0, 0, 0, 0, 0};
        int kk = 0;
#pragma unroll 2
        for (int r = rl; r < p; r += 8) {
          const double e = exp(sv[kk++] - mx);
          den += e;
          const double* vp = vcb + r * 6;
#pragma unroll
          for (int d = 0; d < 6; ++d) o[d] = fma(e, vp[d], o[d]);
        }
#pragma unroll
        for (int off = 1; off < 8; off <<= 1) {
          den += __shfl_xor(den, off);
#pragma unroll
          for (int d = 0; d < 6; ++d) o[d] += __shfl_xor(o[d], off);
        }
        if (rl == 0) {
#pragma unroll
          for (int d = 0; d < 6; ++d) os[h * 6 + d] = o[d] / den;
        }
      }
      __syncthreads();
      // ---- Wo + residual ----
      if (tid < 48)
        xtk[tid] += dot48_row(os, WoT + l * 2304 + tid * 48, (double)par[2112 + l * 48 + tid]);
      __syncthreads();
      // ---- MLP LN ----
      {
        const double2 st = ln_stats48(xtk);
        if (tid < 48)
          anorm[tid] = (xtk[tid] - st.x) * st.y * (double)par[1152 + l * 48 + tid]
                       + (double)par[1344 + l * 48 + tid];
      }
      __syncthreads();
      // ---- MLP1 ----
#pragma unroll
      for (int j = tid; j < 96; j += 64) {
        const double v2 = dot48_row(anorm, W1T + l * 4608 + j * 48, (double)par[2304 + l * 96 + j]);
        hh[j] = v2 > 0 ? v2 : 0;
      }
      __syncthreads();
      // ---- MLP2 (no residual) ----
      if (tid < 48)
        xtk[tid] = dot96_row(hh, W2T + l * 4608 + tid * 96, (double)par[2688 + l * 48 + tid]);
      __syncthreads();
    }

    // ---- sampling: lane owns logit indices tid*8+n (fully in registers) ----
    {
      double lg[8];
      const float* er = embT + (size_t)tid * 384;  // rows tid*8 .. tid*8+7
      double mx = -1e300;
#pragma unroll 2
      for (int n = 0; n < 8; ++n) {
        lg[n] = dot48_row(xtk, er + n * 48, 0.0);
        mx = lg[n] > mx ? lg[n] : mx;
      }
#pragma unroll
      for (int off = 1; off < 64; off <<= 1) {
        const double o2 = __shfl_xor(mx, off); mx = o2 > mx ? o2 : mx;
      }
      double loc[8], run = 0.0;
#pragma unroll
      for (int n = 0; n < 8; ++n) { run += exp(lg[n] - mx); loc[n] = run; }
      double incl = run;
#pragma unroll
      for (int off = 1; off < 64; off <<= 1) {
        const double t2 = __shfl_up(incl, off);
        if (tid >= off) incl += t2;
      }
      const double excl = incl - run;
      const double Ssum = __shfl(incl, 63);
      const double uu = (double)u[step * 512 + b];
      int cnt = 0;
#pragma unroll
      for (int n = 0; n < 8; ++n) cnt += ((excl + loc[n]) / Ssum < uu) ? 1 : 0;
#pragma unroll
      for (int off = 1; off < 64; off <<= 1) cnt += __shfl_xor(cnt, off);
      const int idx = cnt > 511 ? 511 : cnt;
      if (tid < 48) {
        const double sel = (double)embT[(size_t)idx * 48 + tid];
        const double att = xtk[tid];
        out_tok[(size_t)b * 1536 + step * 48 + tid] = (float)((sel + att) - att);  // straight-through fwd
      }
    }
    __syncthreads();
  }
}

// ---------------------------------------------------------------------------
// Launch
// ---------------------------------------------------------------------------
extern "C" void kernel_launch(void* const* d_in, const int* in_sizes, int n_in,
                              void* d_out, int out_size, void* d_ws, size_t ws_size,
                              hipStream_t stream) {
  const float* x      = (const float*)d_in[0];
  const float* u      = (const float*)d_in[1];
  const float* bn_g   = (const float*)d_in[2];
  const float* bn_b   = (const float*)d_in[3];
  const float* conv_w = (const float*)d_in[4];
  const float* conv_b = (const float*)d_in[5];
  const float* tk_W1  = (const float*)d_in[6];
  const float* tk_b1  = (const float*)d_in[7];
  const float* tk_W2  = (const float*)d_in[8];
  const float* tk_b2  = (const float*)d_in[9];
  const float* lnq_g  = (const float*)d_in[10];
  const float* lnq_b  = (const float*)d_in[11];
  const float* Wq     = (const float*)d_in[12];
  const float* bq     = (const float*)d_in[13];
  const float* lnk_g  = (const float*)d_in[14];
  const float* lnk_b  = (const float*)d_in[15];
  const float* Wk     = (const float*)d_in[16];
  const float* bk     = (const float*)d_in[17];
  const float* lnv_g  = (const float*)d_in[18];
  const float* lnv_b  = (const float*)d_in[19];
  const float* Wv     = (const float*)d_in[20];
  const float* bvv    = (const float*)d_in[21];
  const float* Wo     = (const float*)d_in[22];
  const float* bo     = (const float*)d_in[23];
  const float* mln_g  = (const float*)d_in[24];
  const float* mln_b  = (const float*)d_in[25];
  const float* W1     = (const float*)d_in[26];
  const float* b1     = (const float*)d_in[27];
  const float* W2     = (const float*)d_in[28];
  const float* b2     = (const float*)d_in[29];
  const float* emb    = (const float*)d_in[30];
  const float* pos    = (const float*)d_in[31];
  const float* dW1    = (const float*)d_in[32];
  const float* db1    = (const float*)d_in[33];
  const float* dW2    = (const float*)d_in[34];
  const float* db2    = (const float*)d_in[35];
  float* out = (float*)d_out;

  char* w = (char*)d_ws;
  size_t off = 0;
  auto alloc = [&](size_t bytes) {
    size_t o = off;
    off = (off + bytes + 255) & ~(size_t)255;
    return o;
  };
  const size_t o_bnp  = alloc(512 * 14 * 8);
  const size_t o_bns  = alloc(14 * 8);
  const size_t o_xf   = alloc(16777216);   // xf fp64; later reused for split-K partials (12.6MB)
  const size_t o_h    = alloc(33554432);   // h fp64; later reused for out_tok(3.1MB)+dh(6.3MB)+W^T(@16MB)
  const size_t o_toks = alloc(6291456);
  const size_t o_kc   = alloc(50331648);
  const size_t o_vc   = alloc(50331648);

  double* bnp  = (double*)(w + o_bnp);
  double* bns  = (double*)(w + o_bns);
  double* xf   = (double*)(w + o_xf);
  double* hbuf = (double*)(w + o_h);
  double* toks = (double*)(w + o_toks);
  double* kc   = (double*)(w + o_kc);
  double* vc   = (double*)(w + o_vc);
  double* part = (double*)(w + o_xf);                 // reuse (xf dead after G1)
  float*  otok = (float*)(w + o_h);                   // reuse (h dead after G2)
  float*  dh   = (float*)(w + o_h + 4194304);
  // transposed weights live in the dead tail of the h region (16MB..16.4MB;
  // otok ends at 3.1MB, dh ends at 10.5MB -> no overlap). Written after G2.
  float* WqT  = (float*)(w + o_h + 16777216);
  float* WkT  = WqT + 9216;
  float* WvT  = WkT + 9216;
  float* WoT  = WvT + 9216;
  float* W1T  = WoT + 9216;   // 18432 floats
  float* W2T  = W1T + 18432;  // 18432 floats
  float* embT = W2T + 18432;  // 24576 floats

  // 1-2: BatchNorm stats (deterministic fp64)
  bn_partial_kernel<<<512, 256, 0, stream>>>(x, bnp);
  bn_final_kernel<<<1, 64, 0, stream>>>(bnp, bn_g, bn_b, bns);
  // 3: BN-apply + conv + flatten -> xf [512,4096]
  conv_kernel<<<8192, 256, 0, stream>>>(x, conv_w, conv_b, bns, xf);
  // 4: h = relu(xf @ tk_W1 + b1)  [512,8192]  (128x64 tile fp64)
  gemm128_kernel<double, true, true><<<dim3(128, 4, 1), 256, 0, stream>>>(
      xf, tk_W1, tk_b1, hbuf, 512, 8192, 4096, 4096);
  // 5: toks = h @ tk_W2 + b2 (split-K=2 into partials, then reduce)
  gemm128_kernel<double, false, false><<<dim3(24, 4, 2), 256, 0, stream>>>(
      hbuf, tk_W2, nullptr, part, 512, 1536, 8192, 4096);
  reduce2_bias_kernel<<<3072, 256, 0, stream>>>(part, tk_b2, toks, 512 * 1536, 1536);
  // 5b: pre-transpose attention/MLP/embedding weights (hbuf now dead)
  transpose_weights_kernel<<<384, 256, 0, stream>>>(Wq, Wk, Wv, Wo, W1, W2, emb,
      WqT, WkT, WvT, WoT, W1T, W2T, embT);
  // 6: prefill (fills KV caches, positions 0..31)
  prefill_kernel<<<512, 256, 0, stream>>>(toks,
      lnq_g, lnq_b, Wq, bq, lnk_g, lnk_b, Wk, bk, lnv_g, lnv_b, Wv, bvv,
      Wo, bo, mln_g, mln_b, W1, b1, W2, b2, kc, vc);
  // 7: autoregressive loop (32 steps x 4 layers, ONE WAVE per batch elem)
  ar_kernel<<<512, 64, 0, stream>>>(pos, u,
      lnq_g, lnq_b, WqT, bq, lnk_g, lnk_b, WkT, bk, lnv_g, lnv_b, WvT, bvv,
      WoT, bo, mln_g, mln_b, W1T, b1, W2T, b2, embT, kc, vc, otok);
  // 8: decoder (fp32 — post-sampling, continuous path)
  gemm_kernel<float, true, true><<<dim3(48, 8, 1), 256, 0, stream>>>(
      otok, dW1, db1, dh, 512, 3072, 1536, 1536);
  gemm_kernel<float, true, false><<<dim3(28, 8, 1), 256, 0, stream>>>(
      dh, dW2, db2, out, 512, 1792, 3072, 3072);
}

// Round 2
// 5185.912 us; speedup vs baseline: 1.0197x; 1.0197x over previous
//
#include <hip/hip_runtime.h>

// ---------------------------------------------------------------------------
// Dims
// ---------------------------------------------------------------------------
// B=512 A=256 CIN=7 CC=16 D=48 H=8 DH=6 E=512 S=32 T=32 NL=4 STOT=64
// CONV_IN=4096 HID=8192 ENC=1536 DEC_HID=3072 DEC_OUT=1792
static const double SCALE_ = 6.928203230275509;  // sqrt(48)

__device__ inline float  fma_t(float a, float b, float c)  { return fmaf(a, b, c); }
__device__ inline double fma_t(double a, double b, double c){ return fma(a, b, c); }

// ---------------------------------------------------------------------------
// Helpers
// ---------------------------------------------------------------------------
// noinline dual-acc dot (prefill; pairing matches R3 exactly)
__device__ __attribute__((noinline)) double dotW(const double* a,
                                                 const float* W, int n, int ldw,
                                                 double init) {
  double a0 = init, a1 = 0.0;
#pragma unroll 2
  for (int i = 0; i < n; i += 2) {
    a0 = fma(a[i],     (double)W[i * ldw],       a0);
    a1 = fma(a[i + 1], (double)W[(i + 1) * ldw], a1);
  }
  return a0 + a1;
}

// quad-acc dots over a contiguous (pre-transposed) weight row.
// Accumulator pairing (i%4 -> c0..c3) identical to the old dotN<N> -> outputs
// are bit-identical to the previous passing kernels.
__device__ __forceinline__ double dot48_row(const double* a, const float* Wrow, double init) {
  double c0 = init, c1 = 0.0, c2 = 0.0, c3 = 0.0;
#pragma unroll
  for (int i = 0; i < 48; i += 4) {
    const float4 wv = *(const float4*)(Wrow + i);
    c0 = fma(a[i],     (double)wv.x, c0);
    c1 = fma(a[i + 1], (double)wv.y, c1);
    c2 = fma(a[i + 2], (double)wv.z, c2);
    c3 = fma(a[i + 3], (double)wv.w, c3);
  }
  return (c0 + c1) + (c2 + c3);
}

__device__ __forceinline__ double dot96_row(const double* a, const float* Wrow, double init) {
  double c0 = init, c1 = 0.0, c2 = 0.0, c3 = 0.0;
#pragma unroll
  for (int i = 0; i < 96; i += 4) {
    const float4 wv = *(const float4*)(Wrow + i);
    c0 = fma(a[i],     (double)wv.x, c0);
    c1 = fma(a[i + 1], (double)wv.y, c1);
    c2 = fma(a[i + 2], (double)wv.z, c2);
    c3 = fma(a[i + 3], (double)wv.w, c3);
  }
  return (c0 + c1) + (c2 + c3);
}

// LayerNorm stats over 48 elements (redundant per-thread; identical to prev)
__device__ __attribute__((noinline)) double2 ln_stats48(const double* x) {
  double s0 = 0, s1 = 0, q0 = 0, q1 = 0;
#pragma unroll 2
  for (int i = 0; i < 48; i += 2) {
    const double va = x[i], vb = x[i + 1];
    s0 += va; q0 = fma(va, va, q0);
    s1 += vb; q1 = fma(vb, vb, q1);
  }
  const double m = (s0 + s1) / 48.0;
  const double rs = 1.0 / sqrt((q0 + q1) / 48.0 - m * m + 1e-5);
  return make_double2(m, rs);
}

__device__ __attribute__((noinline)) double exp_ni(double x) { return exp(x); }

// ---------------------------------------------------------------------------
// K1: BatchNorm partial sums (deterministic, fp64)
// ---------------------------------------------------------------------------
__global__ __launch_bounds__(256) void bn_partial_kernel(const float* __restrict__ x,
                                                         double* __restrict__ part) {
  __shared__ double sh[256 * 14];
  const int tid = threadIdx.x;
  const int idx = blockIdx.x * 256 + tid;  // (b,a) pair, 0..131071
  const float* p = x + (size_t)idx * 7;
  for (int c = 0; c < 7; ++c) {
    double v = (double)p[c];
    sh[tid * 14 + c] = v;
    sh[tid * 14 + 7 + c] = v * v;
  }
  __syncthreads();
  if (tid < 14) {
    double acc = 0.0;
    for (int t = 0; t < 256; ++t) acc += sh[t * 14 + tid];
    part[blockIdx.x * 14 + tid] = acc;
  }
}

// K2: finalize BN stats -> per-channel scale/shift (fp64)
__global__ void bn_final_kernel(const double* __restrict__ part,
                                const float* __restrict__ g, const float* __restrict__ bb,
                                double* __restrict__ stat) {
  const int c = threadIdx.x;
  if (c < 7) {
    double s = 0.0, s2 = 0.0;
    for (int i = 0; i < 512; ++i) { s += part[i * 14 + c]; s2 += part[i * 14 + 7 + c]; }
    const double mean = s / 131072.0;
    const double var = s2 / 131072.0 - mean * mean;
    const double rstd = 1.0 / sqrt(var + 1e-5);
    const double scale = rstd * (double)g[c];
    stat[c] = scale;                          // x*scale + shift
    stat[7 + c] = (double)bb[c] - mean * scale;
  }
}

// ---------------------------------------------------------------------------
// K3: BN-apply + Conv1d(7->16,k=5,pad=2) + flatten -> xf [512, 16*256] fp64
// ---------------------------------------------------------------------------
__global__ __launch_bounds__(256) void conv_kernel(const float* __restrict__ x,
                                                   const float* __restrict__ wconv,
                                                   const float* __restrict__ cb,
                                                   const double* __restrict__ stat,
                                                   double* __restrict__ xf) {
  __shared__ double wsh[560 + 14];
  const int tid = threadIdx.x;
  for (int i = tid; i < 560; i += 256) wsh[i] = (double)wconv[i];
  for (int i = tid; i < 14; i += 256) wsh[560 + i] = stat[i];
  __syncthreads();
  const int idx = blockIdx.x * 256 + tid;    // b*4096 + o*256 + a
  const int a = idx & 255;
  const int o = (idx >> 8) & 15;
  const int b = idx >> 12;
  double acc = (double)cb[o];
  const float* xb = x + (size_t)b * (256 * 7);
  for (int k = 0; k < 5; ++k) {
    const int pos = a + k - 2;
    if (pos < 0 || pos >= 256) continue;
    const float* xp = xb + pos * 7;
    for (int ci = 0; ci < 7; ++ci) {
      const double xn = (double)xp[ci] * wsh[560 + ci] + wsh[567 + ci];
      acc = fma(xn, wsh[(o * 7 + ci) * 5 + k], acc);
    }
  }
  xf[idx] = acc;
}

// ---------------------------------------------------------------------------
// fp64 GEMM, 128x64 tile, BK=16, 256 threads, 8x4 microtile. (unchanged)
// ---------------------------------------------------------------------------
template <typename T, bool BIAS, bool RELU>
__global__ __launch_bounds__(256) void gemm128_kernel(const T* __restrict__ A,
                                                      const float* __restrict__ Bm,
                                                      const float* __restrict__ bias,
                                                      T* __restrict__ C,
                                                      const int M, const int N, const int K,
                                                      const int kc) {
  __shared__ T As[16][130];  // [k][m], pad +2
  __shared__ T Bs[16][66];   // [k][n], pad +2
  const int tid = threadIdx.x;
  const int tx = tid & 15, ty = tid >> 4;
  const int n0 = blockIdx.x * 64, m0 = blockIdx.y * 128;
  const int k0 = blockIdx.z * kc, kend = k0 + kc;
  const int ar = tid >> 1, ac = (tid & 1) * 8;   // A: 128 rows x 16 k
  const int br = tid >> 4, bc = (tid & 15) * 4;  // B: 16 k x 64 n
  const T* Ap = A + (size_t)(m0 + ar) * K;
  const float* Bp = Bm + (size_t)br * N + n0 + bc;
  T acc[8][4] = {};
  for (int k = k0; k < kend; k += 16) {
    T av8[8];
#pragma unroll
    for (int i = 0; i < 8; ++i) av8[i] = Ap[k + ac + i];
    const float4 bw = *(const float4*)(Bp + (size_t)k * N);
#pragma unroll
    for (int i = 0; i < 8; ++i) As[ac + i][ar] = av8[i];
    Bs[br][bc] = (T)bw.x; Bs[br][bc + 1] = (T)bw.y;
    Bs[br][bc + 2] = (T)bw.z; Bs[br][bc + 3] = (T)bw.w;
    __syncthreads();
#pragma unroll
    for (int kk = 0; kk < 16; ++kk) {
      T a[8], b[4];
#pragma unroll
      for (int i = 0; i < 8; ++i) a[i] = As[kk][ty * 8 + i];
#pragma unroll
      for (int j = 0; j < 4; ++j) b[j] = Bs[kk][tx * 4 + j];
#pragma unroll
      for (int i = 0; i < 8; ++i)
#pragma unroll
        for (int j = 0; j < 4; ++j) acc[i][j] = fma_t(a[i], b[j], acc[i][j]);
    }
    __syncthreads();
  }
  T* Cp = C + (size_t)blockIdx.z * M * N;
#pragma unroll
  for (int i = 0; i < 8; ++i) {
    const int row = m0 + ty * 8 + i;
#pragma unroll
    for (int j = 0; j < 4; ++j) {
      const int col = n0 + tx * 4 + j;
      T v = acc[i][j];
      if (BIAS) v += (T)bias[col];
      if (RELU) v = v > (T)0 ? v : (T)0;
      Cp[(size_t)row * N + col] = v;
    }
  }
}

// Old 64x64 fp32 GEMM (decoder)
template <typename T, bool BIAS, bool RELU>
__global__ __launch_bounds__(256) void gemm_kernel(const T* __restrict__ A,
                                                   const float* __restrict__ Bm,
                                                   const float* __restrict__ bias,
                                                   T* __restrict__ C,
                                                   const int M, const int N, const int K,
                                                   const int kc) {
  __shared__ T As[16][65];
  __shared__ T Bs[16][65];
  const int tid = threadIdx.x;
  const int tx = tid & 15, ty = tid >> 4;
  const int n0 = blockIdx.x * 64, m0 = blockIdx.y * 64;
  const int k0 = blockIdx.z * kc, kend = k0 + kc;
  const int ar = tid >> 2, ac = (tid & 3) * 4;
  const int br = tid >> 4, bc = (tid & 15) * 4;
  const T* Ap = A + (size_t)(m0 + ar) * K;
  const float* Bp = Bm + (size_t)br * N + n0 + bc;
  T acc[4][4] = {};
  for (int k = k0; k < kend; k += 16) {
    const T a0 = Ap[k + ac], a1 = Ap[k + ac + 1], a2 = Ap[k + ac + 2], a3 = Ap[k + ac + 3];
    const float4 bw = *(const float4*)(Bp + (size_t)k * N);
    As[ac][ar] = a0; As[ac + 1][ar] = a1; As[ac + 2][ar] = a2; As[ac + 3][ar] = a3;
    Bs[br][bc] = (T)bw.x; Bs[br][bc + 1] = (T)bw.y; Bs[br][bc + 2] = (T)bw.z; Bs[br][bc + 3] = (T)bw.w;
    __syncthreads();
#pragma unroll
    for (int kk = 0; kk < 16; ++kk) {
      T av[4], bv2[4];
#pragma unroll
      for (int i = 0; i < 4; ++i) av[i] = As[kk][ty * 4 + i];
#pragma unroll
      for (int j = 0; j < 4; ++j) bv2[j] = Bs[kk][tx * 4 + j];
#pragma unroll
      for (int i = 0; i < 4; ++i)
#pragma unroll
        for (int j = 0; j < 4; ++j) acc[i][j] = fma_t(av[i], bv2[j], acc[i][j]);
    }
    __syncthreads();
  }
  T* Cp = C + (size_t)blockIdx.z * M * N;
#pragma unroll
  for (int i = 0; i < 4; ++i) {
    const int row = m0 + ty * 4 + i;
#pragma unroll
    for (int j = 0; j < 4; ++j) {
      const int col = n0 + tx * 4 + j;
      T v = acc[i][j];
      if (BIAS) v += (T)bias[col];
      if (RELU) v = v > (T)0 ? v : (T)0;
      Cp[(size_t)row * N + col] = v;
    }
  }
}

// split-K=2 reduction + bias (fp64, deterministic)
__global__ __launch_bounds__(256) void reduce2_bias_kernel(const double* __restrict__ part,
                                                           const float* __restrict__ bias,
                                                           double* __restrict__ out,
                                                           const int MN, const int N) {
  const int i = blockIdx.x * 256 + threadIdx.x;
  if (i < MN) out[i] = part[i] + part[MN + i] + (double)bias[i % N];
}

// ---------------------------------------------------------------------------
// K4b: pre-transpose weights so each output's weight row is contiguous.
// WqT/WkT/WvT/WoT: [4][48][48] (T[l][j][i] = W[l][i][j])
// W1T: [4][96][48], W2T: [4][48][96], embT: [512][48]
// ---------------------------------------------------------------------------
__global__ __launch_bounds__(256) void transpose_weights_kernel(
    const float* __restrict__ Wq, const float* __restrict__ Wk,
    const float* __restrict__ Wv, const float* __restrict__ Wo,
    const float* __restrict__ W1, const float* __restrict__ W2,
    const float* __restrict__ emb,
    float* __restrict__ WqT, float* __restrict__ WkT,
    float* __restrict__ WvT, float* __restrict__ WoT,
    float* __restrict__ W1T, float* __restrict__ W2T,
    float* __restrict__ embT) {
  const int t = blockIdx.x * 256 + threadIdx.x;  // 0 .. 98303
  if (t < 36864) {                     // Wq|Wk|Wv|Wo: 4 arrays x 4 layers x 48x48
    const int a = t / 9216, r = t - a * 9216;
    const int l = r / 2304, e = r - l * 2304;
    const int i = e / 48, j = e - i * 48;
    const float* src = a == 0 ? Wq : a == 1 ? Wk : a == 2 ? Wv : Wo;
    float* dst = a == 0 ? WqT : a == 1 ? WkT : a == 2 ? WvT : WoT;
    dst[l * 2304 + j * 48 + i] = src[l * 2304 + i * 48 + j];
  } else if (t < 55296) {              // W1 [4][48][96] -> W1T [4][96][48]
    const int t1 = t - 36864;
    const int l = t1 / 4608, e = t1 - l * 4608;
    const int i = e / 96, j = e - i * 96;
    W1T[l * 4608 + j * 48 + i] = W1[l * 4608 + i * 96 + j];
  } else if (t < 73728) {              // W2 [4][96][48] -> W2T [4][48][96]
    const int t2 = t - 55296;
    const int l = t2 / 4608, e = t2 - l * 4608;
    const int i = e / 48, j = e - i * 48;
    W2T[l * 4608 + j * 96 + i] = W2[l * 4608 + i * 48 + j];
  } else {                             // emb [48][512] -> embT [512][48]
    const int t3 = t - 73728;
    const int d = t3 / 512, e = t3 - d * 512;
    embT[e * 48 + d] = emb[d * 512 + e];
  }
}

// ---------------------------------------------------------------------------
// K5: prefill — one block per batch element (unchanged; bit-identical)
// ---------------------------------------------------------------------------
__global__ __launch_bounds__(256) void prefill_kernel(
    const double* __restrict__ toks,
    const float* __restrict__ lnq_g, const float* __restrict__ lnq_b,
    const float* __restrict__ Wq, const float* __restrict__ bq,
    const float* __restrict__ lnk_g, const float* __restrict__ lnk_b,
    const float* __restrict__ Wk, const float* __restrict__ bk,
    const float* __restrict__ lnv_g, const float* __restrict__ lnv_b,
    const float* __restrict__ Wv, const float* __restrict__ bvv,
    const float* __restrict__ Wo, const float* __restrict__ bo,
    const float* __restrict__ mln_g, const float* __restrict__ mln_b,
    const float* __restrict__ W1, const float* __restrict__ b1,
    const float* __restrict__ W2, const float* __restrict__ b2,
    double* __restrict__ kcache, double* __restrict__ vcache) {
  const int b = blockIdx.x, tid = threadIdx.x;
  __shared__ double xcur[1536], abuf[1536], qbuf[1536], kvbuf[3072];
  __shared__ double mean[32], rstd[32];
  double* kb = kvbuf;
  double* vb = kvbuf + 1536;

#pragma unroll 1
  for (int i = tid; i < 1536; i += 256) xcur[i] = toks[(size_t)b * 1536 + i];
  __syncthreads();

#pragma unroll 1
  for (int l = 0; l < 4; ++l) {
    if (tid < 32) {
      double s = 0.0, s2 = 0.0;
#pragma unroll 4
      for (int i = 0; i < 48; ++i) { const double v = xcur[tid * 48 + i]; s += v; s2 += v * v; }
      const double m = s / 48.0;
      mean[tid] = m;
      rstd[tid] = 1.0 / sqrt(s2 / 48.0 - m * m + 1e-5);
    }
    __syncthreads();
    const bool last = (l == 3);

    if (!last) {  // q projection
#pragma unroll 1
      for (int i = tid; i < 1536; i += 256) {
        const int t = i / 48, d = i % 48;
        abuf[i] = (xcur[i] - mean[t]) * rstd[t] * (double)lnq_g[l * 48 + d] + (double)lnq_b[l * 48 + d];
      }
      __syncthreads();
#pragma unroll 1
      for (int i = tid; i < 1536; i += 256) {
        const int t = i / 48, j = i % 48;
        qbuf[i] = dotW(abuf + t * 48, Wq + l * 2304 + j, 48, 48, (double)bq[l * 48 + j]);
      }
      __syncthreads();
    }
    // k projection
#pragma unroll 1
    for (int i = tid; i < 1536; i += 256) {
      const int t = i / 48, d = i % 48;
      abuf[i] = (xcur[i] - mean[t]) * rstd[t] * (double)lnk_g[l * 48 + d] + (double)lnk_b[l * 48 + d];
    }
    __syncthreads();
#pragma unroll 1
    for (int i = tid; i < 1536; i += 256) {
      const int t = i / 48, j = i % 48;
      kb[i] = dotW(abuf + t * 48, Wk + l * 2304 + j, 48, 48, (double)bk[l * 48 + j]);
    }
    __syncthreads();
    // v projection
#pragma unroll 1
    for (int i = tid; i < 1536; i += 256) {
      const int t = i / 48, d = i % 48;
      abuf[i] = (xcur[i] - mean[t]) * rstd[t] * (double)lnv_g[l * 48 + d] + (double)lnv_b[l * 48 + d];
    }
    __syncthreads();
#pragma unroll 1
    for (int i = tid; i < 1536; i += 256) {
      const int t = i / 48, j = i % 48;
      vb[i] = dotW(abuf + t * 48, Wv + l * 2304 + j, 48, 48, (double)bvv[l * 48 + j]);
    }
    __syncthreads();
    // store k,v to cache at pos t
#pragma unroll 1
    for (int i = tid; i < 1536; i += 256) {
      const int t = i / 48, j = i % 48;
      const int h = j / 6, d = j % 6;
      const size_t ci = ((((size_t)b * 4 + l) * 8 + h) * 64 + t) * 6 + d;
      kcache[ci] = kb[i];
      vcache[ci] = vb[i];
    }

    if (!last) {
      // attention: thread = (token t, head h). mask only (t=0, j=31).
      const int t = tid >> 3, h = tid & 7;
      const double* qp = qbuf + t * 48 + h * 6;
      const double q0 = qp[0], q1 = qp[1], q2 = qp[2], q3 = qp[3], q4 = qp[4], q5 = qp[5];
      double mx = -1e300;
#pragma unroll 4
      for (int j = 0; j < 32; ++j) {
        const double* kp = kb + j * 48 + h * 6;
        double sv = q0 * kp[0];
        sv = fma(q1, kp[1], sv); sv = fma(q2, kp[2], sv); sv = fma(q3, kp[3], sv);
        sv = fma(q4, kp[4], sv); sv = fma(q5, kp[5], sv);
        sv /= SCALE_;
        if (t == 0 && j == 31) sv -= 999.0;
        mx = sv > mx ? sv : mx;
      }
      double den = 0, o0 = 0, o1 = 0, o2 = 0, o3 = 0, o4 = 0, o5 = 0;
#pragma unroll 4
      for (int j = 0; j < 32; ++j) {
        const double* kp = kb + j * 48 + h * 6;
        double sv = q0 * kp[0];
        sv = fma(q1, kp[1], sv); sv = fma(q2, kp[2], sv); sv = fma(q3, kp[3], sv);
        sv = fma(q4, kp[4], sv); sv = fma(q5, kp[5], sv);
        sv /= SCALE_;
        if (t == 0 && j == 31) sv -= 999.0;
        const double e = exp_ni(sv - mx);
        den += e;
        const double* vp = vb + j * 48 + h * 6;
        o0 = fma(e, vp[0], o0); o1 = fma(e, vp[1], o1); o2 = fma(e, vp[2], o2);
        o3 = fma(e, vp[3], o3); o4 = fma(e, vp[4], o4); o5 = fma(e, vp[5], o5);
      }
      abuf[t * 48 + h * 6 + 0] = o0 / den;
      abuf[t * 48 + h * 6 + 1] = o1 / den;
      abuf[t * 48 + h * 6 + 2] = o2 / den;
      abuf[t * 48 + h * 6 + 3] = o3 / den;
      abuf[t * 48 + h * 6 + 4] = o4 / den;
      abuf[t * 48 + h * 6 + 5] = o5 / den;
      __syncthreads();
      // Wo + residual
#pragma unroll 1
      for (int i = tid; i < 1536; i += 256) {
        const int t2 = i / 48, j = i % 48;
        xcur[i] += dotW(abuf + t2 * 48, Wo + l * 2304 + j, 48, 48, (double)bo[l * 48 + j]);
      }
      __syncthreads();
      // MLP LN
      if (tid < 32) {
        double s = 0.0, s2 = 0.0;
#pragma unroll 4
        for (int i = 0; i < 48; ++i) { const double v = xcur[tid * 48 + i]; s += v; s2 += v * v; }
        const double m = s / 48.0;
        mean[tid] = m;
        rstd[tid] = 1.0 / sqrt(s2 / 48.0 - m * m + 1e-5);
      }
      __syncthreads();
#pragma unroll 1
      for (int i = tid; i < 1536; i += 256) {
        const int t2 = i / 48, d = i % 48;
        qbuf[i] = (xcur[i] - mean[t2]) * rstd[t2] * (double)mln_g[l * 48 + d] + (double)mln_b[l * 48 + d];
      }
      __syncthreads();
#pragma unroll 1
      for (int i = tid; i < 3072; i += 256) {
        const int t2 = i / 96, jj = i % 96;
        const double acc = dotW(qbuf + t2 * 48, W1 + l * 4608 + jj, 48, 96, (double)b1[l * 96 + jj]);
        kvbuf[i] = acc > 0 ? acc : 0;
      }
      __syncthreads();
#pragma unroll 1
      for (int i = tid; i < 1536; i += 256) {
        const int t2 = i / 48, j = i % 48;
        abuf[i] = dotW(kvbuf + t2 * 96, W2 + l * 4608 + j, 96, 48, (double)b2[l * 48 + j]);
      }
      __syncthreads();
#pragma unroll 1
      for (int i = tid; i < 1536; i += 256) xcur[i] = abuf[i];
      __syncthreads();
    }
  }
}

// ---------------------------------------------------------------------------
// K6: autoregressive loop — one block (256 thr) per batch element.
//   KV cache never touches global memory inside the loop:
//     K cache: LDS fp32 [4][8][64][6]  (48 KB)
//     V cache: registers fp32, lane (h=tid>>5, r=tid&31) owns rows r and r+32
//   Weights read directly from pre-transposed global rows (L2-hot).
//   All dot products keep the proven accumulation pairing -> same sampling.
// ---------------------------------------------------------------------------
__global__ __launch_bounds__(256, 2) void ar_kernel(
    const float* __restrict__ pos_enc, const float* __restrict__ u,
    const float* __restrict__ lnq_g, const float* __restrict__ lnq_b,
    const float* __restrict__ WqT, const float* __restrict__ bq,
    const float* __restrict__ lnk_g, const float* __restrict__ lnk_b,
    const float* __restrict__ WkT, const float* __restrict__ bk,
    const float* __restrict__ lnv_g, const float* __restrict__ lnv_b,
    const float* __restrict__ WvT, const float* __restrict__ bvv,
    const float* __restrict__ WoT, const float* __restrict__ bo,
    const float* __restrict__ mln_g, const float* __restrict__ mln_b,
    const float* __restrict__ W1T, const float* __restrict__ b1,
    const float* __restrict__ W2T, const float* __restrict__ b2,
    const float* __restrict__ embT,
    const double* __restrict__ kcache, const double* __restrict__ vcache,
    float* __restrict__ out_tok) {
  const int b = blockIdx.x, tid = threadIdx.x;
  __shared__ float ksh[4][8][64][6];   // 49152 B: K cache fp32
  __shared__ double xtk[48], anorm[144], qs[48], os[48], hh[96];
  __shared__ float vnew[48];
  __shared__ double probs[512], red[4];
  // par layout (floats):
  //    0 lnq_g |  192 lnq_b |  384 lnk_g |  576 lnk_b |  768 lnv_g |  960 lnv_b
  // 1152 mln_g | 1344 mln_b | 1536 bq | 1728 bk | 1920 bv | 2112 bo
  // 2304 b1[384] | 2688 b2[192]   -> total 2880
  __shared__ float par[2880];
  {
    const float* srcs[14] = {lnq_g, lnq_b, lnk_g, lnk_b, lnv_g, lnv_b, mln_g, mln_b,
                             bq, bk, bvv, bo, b1, b2};
    const int sz[14] = {192, 192, 192, 192, 192, 192, 192, 192, 192, 192, 192, 192, 384, 192};
    int base = 0;
#pragma unroll 1
    for (int a2 = 0; a2 < 14; ++a2) {
      for (int i = tid; i < sz[a2]; i += 256) par[base + i] = srcs[a2][i];
      base += sz[a2];
    }
  }
  // preload K positions 0..31 (prefill output) into LDS as fp32
#pragma unroll 1
  for (int m = tid; m < 6144; m += 256) {
    const int d = m % 6, t2 = (m / 6) % 32, h2 = (m / 192) % 8, l2 = m / 1536;
    ksh[l2][h2][t2][d] =
        (float)kcache[((((size_t)b * 4 + l2) * 8 + h2) * 64 + t2) * 6 + d];
  }
  // preload V positions 0..31 into lane registers (lane = head h, row r)
  const int hl = tid >> 5, rl = tid & 31;
  float vlo[4][6], vhi[4][6];
#pragma unroll
  for (int l2 = 0; l2 < 4; ++l2)
#pragma unroll
    for (int d = 0; d < 6; ++d) {
      vlo[l2][d] = (float)vcache[((((size_t)b * 4 + l2) * 8 + hl) * 64 + rl) * 6 + d];
      vhi[l2][d] = 0.0f;
    }
  __syncthreads();

#pragma unroll 1
  for (int step = 0; step < 32; ++step) {
    const int p = 32 + step;
    if (tid < 48) xtk[tid] = (double)pos_enc[step * 48 + tid];
    __syncthreads();

#pragma unroll
    for (int l = 0; l < 4; ++l) {
      // ---- LN1 (redundant stats) + 3 norms (144 outputs) ----
      {
        const double2 st = ln_stats48(xtk);
        if (tid < 144) {
          const int which = tid / 48, d = tid - which * 48;
          const float* gp = par + 384 * which;   // lnq_g / lnk_g / lnv_g
          const float* bp = gp + 192;
          anorm[tid] = (xtk[d] - st.x) * st.y * (double)gp[l * 48 + d] + (double)bp[l * 48 + d];
        }
      }
      __syncthreads();
      // ---- q,k,v projections; k -> LDS cache, v -> bounce buffer ----
      if (tid < 144) {
        const int which = tid / 48, j = tid - which * 48;
        const float* WT = which == 0 ? WqT : which == 1 ? WkT : WvT;
        const float* bbp = par + 1536 + 192 * which;  // bq / bk / bv
        const double acc = dot48_row(anorm + which * 48, WT + l * 2304 + j * 48,
                                     (double)bbp[l * 48 + j]);
        if (which == 0) {
          qs[j] = acc;
        } else {
          const int h2 = j / 6, d2 = j - h2 * 6;
          if (which == 1) ksh[l][h2][p][d2] = (float)acc;
          else            vnew[j] = (float)acc;
        }
      }
      __syncthreads();
      // owner lane of row p picks up the new v (p>=32 always -> vhi)
      if (rl == (p & 31)) {
#pragma unroll
        for (int d = 0; d < 6; ++d) vhi[l][d] = vnew[hl * 6 + d];
      }
      // ---- attention over [0,p): 32 lanes per head, rows rl and rl+32 ----
      {
        const float* kp1 = &ksh[l][hl][rl][0];
        const double qv0 = qs[hl * 6 + 0], qv1 = qs[hl * 6 + 1], qv2 = qs[hl * 6 + 2],
                     qv3 = qs[hl * 6 + 3], qv4 = qs[hl * 6 + 4], qv5 = qs[hl * 6 + 5];
        const bool has2 = (rl + 32) < p;
        double sv1 = qv0 * (double)kp1[0];
        sv1 = fma(qv1, (double)kp1[1], sv1); sv1 = fma(qv2, (double)kp1[2], sv1);
        sv1 = fma(qv3, (double)kp1[3], sv1); sv1 = fma(qv4, (double)kp1[4], sv1);
        sv1 = fma(qv5, (double)kp1[5], sv1);
        sv1 /= SCALE_;
        double sv2 = -1e300;
        if (has2) {
          const float* kp2 = &ksh[l][hl][rl + 32][0];
          double t2 = qv0 * (double)kp2[0];
          t2 = fma(qv1, (double)kp2[1], t2); t2 = fma(qv2, (double)kp2[2], t2);
          t2 = fma(qv3, (double)kp2[3], t2); t2 = fma(qv4, (double)kp2[4], t2);
          t2 = fma(qv5, (double)kp2[5], t2);
          sv2 = t2 / SCALE_;
        }
        double mx = sv1 > sv2 ? sv1 : sv2;
#pragma unroll
        for (int off = 1; off < 32; off <<= 1) { const double o2 = __shfl_xor(mx, off); mx = o2 > mx ? o2 : mx; }
        const double e1 = exp(sv1 - mx);
        const double e2 = has2 ? exp(sv2 - mx) : 0.0;
        double den = e1 + e2;
        double o[6];
#pragma unroll
        for (int d = 0; d < 6; ++d) o[d] = e1 * (double)vlo[l][d];
        if (has2) {
#pragma unroll
          for (int d = 0; d < 6; ++d) o[d] = fma(e2, (double)vhi[l][d], o[d]);
        }
#pragma unroll
        for (int off = 1; off < 32; off <<= 1) {
          den += __shfl_xor(den, off);
#pragma unroll
          for (int d = 0; d < 6; ++d) o[d] += __shfl_xor(o[d], off);
        }
        if (rl == 0) {
#pragma unroll
          for (int d = 0; d < 6; ++d) os[hl * 6 + d] = o[d] / den;
        }
      }
      __syncthreads();
      // ---- Wo + residual ----
      if (tid < 48)
        xtk[tid] += dot48_row(os, WoT + l * 2304 + tid * 48, (double)par[2112 + l * 48 + tid]);
      __syncthreads();
      // ---- MLP LN ----
      {
        const double2 st = ln_stats48(xtk);
        if (tid < 48)
          anorm[tid] = (xtk[tid] - st.x) * st.y * (double)par[1152 + l * 48 + tid]
                       + (double)par[1344 + l * 48 + tid];
      }
      __syncthreads();
      // ---- MLP1 ----
      if (tid < 96) {
        const double v2 = dot48_row(anorm, W1T + l * 4608 + tid * 48, (double)par[2304 + l * 96 + tid]);
        hh[tid] = v2 > 0 ? v2 : 0;
      }
      __syncthreads();
      // ---- MLP2 (no residual) ----
      if (tid < 48)
        xtk[tid] = dot96_row(hh, W2T + l * 4608 + tid * 96, (double)par[2688 + l * 48 + tid]);
      __syncthreads();
    }

    // ---- sampling (proven 256-thread scheme; embT rows are contiguous) ----
    {
      const double lg1 = dot48_row(xtk, embT + (size_t)tid * 48, 0.0);
      const double lg2 = dot48_row(xtk, embT + (size_t)(256 + tid) * 48, 0.0);
      double mx = lg1 > lg2 ? lg1 : lg2;
#pragma unroll
      for (int off = 1; off < 64; off <<= 1) { const double o2 = __shfl_xor(mx, off); mx = o2 > mx ? o2 : mx; }
      if ((tid & 63) == 0) red[tid >> 6] = mx;
      __syncthreads();
      {
        const double m0 = red[0] > red[1] ? red[0] : red[1];
        const double m1 = red[2] > red[3] ? red[2] : red[3];
        mx = m0 > m1 ? m0 : m1;
      }
      probs[tid] = exp(lg1 - mx);
      probs[tid + 256] = exp(lg2 - mx);
      __syncthreads();
      if (tid < 64) {
        const int lane = tid;
        double loc[8], run = 0;
#pragma unroll
        for (int n2 = 0; n2 < 8; ++n2) { run += probs[lane * 8 + n2]; loc[n2] = run; }
        double incl = run;
#pragma unroll
        for (int off = 1; off < 64; off <<= 1) {
          const double t2 = __shfl_up(incl, off);
          if (lane >= off) incl += t2;
        }
        const double excl = incl - run;
        const double Ssum = __shfl(incl, 63);
        const double uu = (double)u[step * 512 + b];
        int cnt = 0;
#pragma unroll
        for (int n2 = 0; n2 < 8; ++n2) cnt += ((excl + loc[n2]) / Ssum < uu) ? 1 : 0;
#pragma unroll
        for (int off = 1; off < 64; off <<= 1) cnt += __shfl_xor(cnt, off);
        const int idx = cnt > 511 ? 511 : cnt;
        if (lane < 48) {
          const double sel = (double)embT[(size_t)idx * 48 + lane];
          const double att = xtk[lane];
          out_tok[(size_t)b * 1536 + step * 48 + lane] = (float)((sel + att) - att);  // straight-through fwd
        }
      }
      __syncthreads();
    }
  }
}

// ---------------------------------------------------------------------------
// Launch
// ---------------------------------------------------------------------------
extern "C" void kernel_launch(void* const* d_in, const int* in_sizes, int n_in,
                              void* d_out, int out_size, void* d_ws, size_t ws_size,
                              hipStream_t stream) {
  const float* x      = (const float*)d_in[0];
  const float* u      = (const float*)d_in[1];
  const float* bn_g   = (const float*)d_in[2];
  const float* bn_b   = (const float*)d_in[3];
  const float* conv_w = (const float*)d_in[4];
  const float* conv_b = (const float*)d_in[5];
  const float* tk_W1  = (const float*)d_in[6];
  const float* tk_b1  = (const float*)d_in[7];
  const float* tk_W2  = (const float*)d_in[8];
  const float* tk_b2  = (const float*)d_in[9];
  const float* lnq_g  = (const float*)d_in[10];
  const float* lnq_b  = (const float*)d_in[11];
  const float* Wq     = (const float*)d_in[12];
  const float* bq     = (const float*)d_in[13];
  const float* lnk_g  = (const float*)d_in[14];
  const float* lnk_b  = (const float*)d_in[15];
  const float* Wk     = (const float*)d_in[16];
  const float* bk     = (const float*)d_in[17];
  const float* lnv_g  = (const float*)d_in[18];
  const float* lnv_b  = (const float*)d_in[19];
  const float* Wv     = (const float*)d_in[20];
  const float* bvv    = (const float*)d_in[21];
  const float* Wo     = (const float*)d_in[22];
  const float* bo     = (const float*)d_in[23];
  const float* mln_g  = (const float*)d_in[24];
  const float* mln_b  = (const float*)d_in[25];
  const float* W1     = (const float*)d_in[26];
  const float* b1     = (const float*)d_in[27];
  const float* W2     = (const float*)d_in[28];
  const float* b2     = (const float*)d_in[29];
  const float* emb    = (const float*)d_in[30];
  const float* pos    = (const float*)d_in[31];
  const float* dW1    = (const float*)d_in[32];
  const float* db1    = (const float*)d_in[33];
  const float* dW2    = (const float*)d_in[34];
  const float* db2    = (const float*)d_in[35];
  float* out = (float*)d_out;

  char* w = (char*)d_ws;
  size_t off = 0;
  auto alloc = [&](size_t bytes) {
    size_t o = off;
    off = (off + bytes + 255) & ~(size_t)255;
    return o;
  };
  const size_t o_bnp  = alloc(512 * 14 * 8);
  const size_t o_bns  = alloc(14 * 8);
  const size_t o_xf   = alloc(16777216);   // xf fp64; later reused for split-K partials (12.6MB)
  const size_t o_h    = alloc(33554432);   // h fp64; later reused for out_tok(3.1MB)+dh(6.3MB)+W^T(@16MB)
  const size_t o_toks = alloc(6291456);
  const size_t o_kc   = alloc(50331648);
  const size_t o_vc   = alloc(50331648);

  double* bnp  = (double*)(w + o_bnp);
  double* bns  = (double*)(w + o_bns);
  double* xf   = (double*)(w + o_xf);
  double* hbuf = (double*)(w + o_h);
  double* toks = (double*)(w + o_toks);
  double* kc   = (double*)(w + o_kc);
  double* vc   = (double*)(w + o_vc);
  double* part = (double*)(w + o_xf);                 // reuse (xf dead after G1)
  float*  otok = (float*)(w + o_h);                   // reuse (h dead after G2)
  float*  dh   = (float*)(w + o_h + 4194304);
  // transposed weights live in the dead tail of the h region (16MB..16.4MB;
  // otok ends at 3.1MB, dh ends at 10.5MB -> no overlap). Written after G2.
  float* WqT  = (float*)(w + o_h + 16777216);
  float* WkT  = WqT + 9216;
  float* WvT  = WkT + 9216;
  float* WoT  = WvT + 9216;
  float* W1T  = WoT + 9216;   // 18432 floats
  float* W2T  = W1T + 18432;  // 18432 floats
  float* embT = W2T + 18432;  // 24576 floats

  // 1-2: BatchNorm stats (deterministic fp64)
  bn_partial_kernel<<<512, 256, 0, stream>>>(x, bnp);
  bn_final_kernel<<<1, 64, 0, stream>>>(bnp, bn_g, bn_b, bns);
  // 3: BN-apply + conv + flatten -> xf [512,4096]
  conv_kernel<<<8192, 256, 0, stream>>>(x, conv_w, conv_b, bns, xf);
  // 4: h = relu(xf @ tk_W1 + b1)  [512,8192]  (128x64 tile fp64)
  gemm128_kernel<double, true, true><<<dim3(128, 4, 1), 256, 0, stream>>>(
      xf, tk_W1, tk_b1, hbuf, 512, 8192, 4096, 4096);
  // 5: toks = h @ tk_W2 + b2 (split-K=2 into partials, then reduce)
  gemm128_kernel<double, false, false><<<dim3(24, 4, 2), 256, 0, stream>>>(
      hbuf, tk_W2, nullptr, part, 512, 1536, 8192, 4096);
  reduce2_bias_kernel<<<3072, 256, 0, stream>>>(part, tk_b2, toks, 512 * 1536, 1536);
  // 5b: pre-transpose attention/MLP/embedding weights (hbuf now dead)
  transpose_weights_kernel<<<384, 256, 0, stream>>>(Wq, Wk, Wv, Wo, W1, W2, emb,
      WqT, WkT, WvT, WoT, W1T, W2T, embT);
  // 6: prefill (fills KV caches, positions 0..31)
  prefill_kernel<<<512, 256, 0, stream>>>(toks,
      lnq_g, lnq_b, Wq, bq, lnk_g, lnk_b, Wk, bk, lnv_g, lnv_b, Wv, bvv,
      Wo, bo, mln_g, mln_b, W1, b1, W2, b2, kc, vc);
  // 7: autoregressive loop (32 steps x 4 layers; KV resident in LDS+regs)
  ar_kernel<<<512, 256, 0, stream>>>(pos, u,
      lnq_g, lnq_b, WqT, bq, lnk_g, lnk_b, WkT, bk, lnv_g, lnv_b, WvT, bvv,
      WoT, bo, mln_g, mln_b, W1T, b1, W2T, b2, embT, kc, vc, otok);
  // 8: decoder (fp32 — post-sampling, continuous path)
  gemm_kernel<float, true, true><<<dim3(48, 8, 1), 256, 0, stream>>>(
      otok, dW1, db1, dh, 512, 3072, 1536, 1536);
  gemm_kernel<float, true, false><<<dim3(28, 8, 1), 256, 0, stream>>>(
      dh, dW2, db2, out, 512, 1792, 3072, 3072);
}

// Round 4
// 5160.070 us; speedup vs baseline: 1.0248x; 1.0050x over previous
//
#include <hip/hip_runtime.h>

// ---------------------------------------------------------------------------
// Dims
// ---------------------------------------------------------------------------
// B=512 A=256 CIN=7 CC=16 D=48 H=8 DH=6 E=512 S=32 T=32 NL=4 STOT=64
// CONV_IN=4096 HID=8192 ENC=1536 DEC_HID=3072 DEC_OUT=1792
static const double SCALE_ = 6.928203230275509;  // sqrt(48)

__device__ inline float  fma_t(float a, float b, float c)  { return fmaf(a, b, c); }
__device__ inline double fma_t(double a, double b, double c){ return fma(a, b, c); }

// ---------------------------------------------------------------------------
// Helpers
// ---------------------------------------------------------------------------
// noinline dual-acc dot (prefill; pairing matches R3 exactly)
__device__ __attribute__((noinline)) double dotW(const double* a,
                                                 const float* W, int n, int ldw,
                                                 double init) {
  double a0 = init, a1 = 0.0;
#pragma unroll 2
  for (int i = 0; i < n; i += 2) {
    a0 = fma(a[i],     (double)W[i * ldw],       a0);
    a1 = fma(a[i + 1], (double)W[(i + 1) * ldw], a1);
  }
  return a0 + a1;
}

// quad-acc dot with stride (sampling; pairing i%4 -> c0..c3, proven)
template <int N, typename WP>
__device__ __forceinline__ double dotN(const double* a, WP W, int ldw, double init) {
  double c0 = init, c1 = 0.0, c2 = 0.0, c3 = 0.0;
#pragma unroll
  for (int i = 0; i < N; i += 4) {
    c0 = fma(a[i],     (double)W[i * ldw],       c0);
    c1 = fma(a[i + 1], (double)W[(i + 1) * ldw], c1);
    c2 = fma(a[i + 2], (double)W[(i + 2) * ldw], c2);
    c3 = fma(a[i + 3], (double)W[(i + 3) * ldw], c3);
  }
  return (c0 + c1) + (c2 + c3);
}

// quad-acc dots over a contiguous weight row (global or LDS; float4 reads).
// Accumulator pairing identical to dotN -> bit-identical results.
__device__ __forceinline__ double dot48_row(const double* a, const float* Wrow, double init) {
  double c0 = init, c1 = 0.0, c2 = 0.0, c3 = 0.0;
#pragma unroll
  for (int i = 0; i < 48; i += 4) {
    const float4 wv = *(const float4*)(Wrow + i);
    c0 = fma(a[i],     (double)wv.x, c0);
    c1 = fma(a[i + 1], (double)wv.y, c1);
    c2 = fma(a[i + 2], (double)wv.z, c2);
    c3 = fma(a[i + 3], (double)wv.w, c3);
  }
  return (c0 + c1) + (c2 + c3);
}

__device__ __forceinline__ double dot96_row(const double* a, const float* Wrow, double init) {
  double c0 = init, c1 = 0.0, c2 = 0.0, c3 = 0.0;
#pragma unroll
  for (int i = 0; i < 96; i += 4) {
    const float4 wv = *(const float4*)(Wrow + i);
    c0 = fma(a[i],     (double)wv.x, c0);
    c1 = fma(a[i + 1], (double)wv.y, c1);
    c2 = fma(a[i + 2], (double)wv.z, c2);
    c3 = fma(a[i + 3], (double)wv.w, c3);
  }
  return (c0 + c1) + (c2 + c3);
}

// LayerNorm stats over 48 elements (redundant per-thread; identical to prev)
__device__ __attribute__((noinline)) double2 ln_stats48(const double* x) {
  double s0 = 0, s1 = 0, q0 = 0, q1 = 0;
#pragma unroll 2
  for (int i = 0; i < 48; i += 2) {
    const double va = x[i], vb = x[i + 1];
    s0 += va; q0 = fma(va, va, q0);
    s1 += vb; q1 = fma(vb, vb, q1);
  }
  const double m = (s0 + s1) / 48.0;
  const double rs = 1.0 / sqrt((q0 + q1) / 48.0 - m * m + 1e-5);
  return make_double2(m, rs);
}

__device__ __attribute__((noinline)) double exp_ni(double x) { return exp(x); }

// ---------------------------------------------------------------------------
// K1: BatchNorm partial sums (deterministic, fp64)
// ---------------------------------------------------------------------------
__global__ __launch_bounds__(256) void bn_partial_kernel(const float* __restrict__ x,
                                                         double* __restrict__ part) {
  __shared__ double sh[256 * 14];
  const int tid = threadIdx.x;
  const int idx = blockIdx.x * 256 + tid;  // (b,a) pair, 0..131071
  const float* p = x + (size_t)idx * 7;
  for (int c = 0; c < 7; ++c) {
    double v = (double)p[c];
    sh[tid * 14 + c] = v;
    sh[tid * 14 + 7 + c] = v * v;
  }
  __syncthreads();
  if (tid < 14) {
    double acc = 0.0;
    for (int t = 0; t < 256; ++t) acc += sh[t * 14 + tid];
    part[blockIdx.x * 14 + tid] = acc;
  }
}

// K2: finalize BN stats -> per-channel scale/shift (fp64)
__global__ void bn_final_kernel(const double* __restrict__ part,
                                const float* __restrict__ g, const float* __restrict__ bb,
                                double* __restrict__ stat) {
  const int c = threadIdx.x;
  if (c < 7) {
    double s = 0.0, s2 = 0.0;
    for (int i = 0; i < 512; ++i) { s += part[i * 14 + c]; s2 += part[i * 14 + 7 + c]; }
    const double mean = s / 131072.0;
    const double var = s2 / 131072.0 - mean * mean;
    const double rstd = 1.0 / sqrt(var + 1e-5);
    const double scale = rstd * (double)g[c];
    stat[c] = scale;                          // x*scale + shift
    stat[7 + c] = (double)bb[c] - mean * scale;
  }
}

// ---------------------------------------------------------------------------
// K3: BN-apply + Conv1d(7->16,k=5,pad=2) + flatten -> xf [512, 16*256] fp64
// ---------------------------------------------------------------------------
__global__ __launch_bounds__(256) void conv_kernel(const float* __restrict__ x,
                                                   const float* __restrict__ wconv,
                                                   const float* __restrict__ cb,
                                                   const double* __restrict__ stat,
                                                   double* __restrict__ xf) {
  __shared__ double wsh[560 + 14];
  const int tid = threadIdx.x;
  for (int i = tid; i < 560; i += 256) wsh[i] = (double)wconv[i];
  for (int i = tid; i < 14; i += 256) wsh[560 + i] = stat[i];
  __syncthreads();
  const int idx = blockIdx.x * 256 + tid;    // b*4096 + o*256 + a
  const int a = idx & 255;
  const int o = (idx >> 8) & 15;
  const int b = idx >> 12;
  double acc = (double)cb[o];
  const float* xb = x + (size_t)b * (256 * 7);
  for (int k = 0; k < 5; ++k) {
    const int pos = a + k - 2;
    if (pos < 0 || pos >= 256) continue;
    const float* xp = xb + pos * 7;
    for (int ci = 0; ci < 7; ++ci) {
      const double xn = (double)xp[ci] * wsh[560 + ci] + wsh[567 + ci];
      acc = fma(xn, wsh[(o * 7 + ci) * 5 + k], acc);
    }
  }
  xf[idx] = acc;
}

// ---------------------------------------------------------------------------
// fp64 GEMM, 128x64 tile, BK=16, 256 threads, 8x4 microtile. (unchanged)
// ---------------------------------------------------------------------------
template <typename T, bool BIAS, bool RELU>
__global__ __launch_bounds__(256) void gemm128_kernel(const T* __restrict__ A,
                                                      const float* __restrict__ Bm,
                                                      const float* __restrict__ bias,
                                                      T* __restrict__ C,
                                                      const int M, const int N, const int K,
                                                      const int kc) {
  __shared__ T As[16][130];  // [k][m], pad +2
  __shared__ T Bs[16][66];   // [k][n], pad +2
  const int tid = threadIdx.x;
  const int tx = tid & 15, ty = tid >> 4;
  const int n0 = blockIdx.x * 64, m0 = blockIdx.y * 128;
  const int k0 = blockIdx.z * kc, kend = k0 + kc;
  const int ar = tid >> 1, ac = (tid & 1) * 8;   // A: 128 rows x 16 k
  const int br = tid >> 4, bc = (tid & 15) * 4;  // B: 16 k x 64 n
  const T* Ap = A + (size_t)(m0 + ar) * K;
  const float* Bp = Bm + (size_t)br * N + n0 + bc;
  T acc[8][4] = {};
  for (int k = k0; k < kend; k += 16) {
    T av8[8];
#pragma unroll
    for (int i = 0; i < 8; ++i) av8[i] = Ap[k + ac + i];
    const float4 bw = *(const float4*)(Bp + (size_t)k * N);
#pragma unroll
    for (int i = 0; i < 8; ++i) As[ac + i][ar] = av8[i];
    Bs[br][bc] = (T)bw.x; Bs[br][bc + 1] = (T)bw.y;
    Bs[br][bc + 2] = (T)bw.z; Bs[br][bc + 3] = (T)bw.w;
    __syncthreads();
#pragma unroll
    for (int kk = 0; kk < 16; ++kk) {
      T a[8], b[4];
#pragma unroll
      for (int i = 0; i < 8; ++i) a[i] = As[kk][ty * 8 + i];
#pragma unroll
      for (int j = 0; j < 4; ++j) b[j] = Bs[kk][tx * 4 + j];
#pragma unroll
      for (int i = 0; i < 8; ++i)
#pragma unroll
        for (int j = 0; j < 4; ++j) acc[i][j] = fma_t(a[i], b[j], acc[i][j]);
    }
    __syncthreads();
  }
  T* Cp = C + (size_t)blockIdx.z * M * N;
#pragma unroll
  for (int i = 0; i < 8; ++i) {
    const int row = m0 + ty * 8 + i;
#pragma unroll
    for (int j = 0; j < 4; ++j) {
      const int col = n0 + tx * 4 + j;
      T v = acc[i][j];
      if (BIAS) v += (T)bias[col];
      if (RELU) v = v > (T)0 ? v : (T)0;
      Cp[(size_t)row * N + col] = v;
    }
  }
}

// Old 64x64 fp32 GEMM (decoder)
template <typename T, bool BIAS, bool RELU>
__global__ __launch_bounds__(256) void gemm_kernel(const T* __restrict__ A,
                                                   const float* __restrict__ Bm,
                                                   const float* __restrict__ bias,
                                                   T* __restrict__ C,
                                                   const int M, const int N, const int K,
                                                   const int kc) {
  __shared__ T As[16][65];
  __shared__ T Bs[16][65];
  const int tid = threadIdx.x;
  const int tx = tid & 15, ty = tid >> 4;
  const int n0 = blockIdx.x * 64, m0 = blockIdx.y * 64;
  const int k0 = blockIdx.z * kc, kend = k0 + kc;
  const int ar = tid >> 2, ac = (tid & 3) * 4;
  const int br = tid >> 4, bc = (tid & 15) * 4;
  const T* Ap = A + (size_t)(m0 + ar) * K;
  const float* Bp = Bm + (size_t)br * N + n0 + bc;
  T acc[4][4] = {};
  for (int k = k0; k < kend; k += 16) {
    const T a0 = Ap[k + ac], a1 = Ap[k + ac + 1], a2 = Ap[k + ac + 2], a3 = Ap[k + ac + 3];
    const float4 bw = *(const float4*)(Bp + (size_t)k * N);
    As[ac][ar] = a0; As[ac + 1][ar] = a1; As[ac + 2][ar] = a2; As[ac + 3][ar] = a3;
    Bs[br][bc] = (T)bw.x; Bs[br][bc + 1] = (T)bw.y; Bs[br][bc + 2] = (T)bw.z; Bs[br][bc + 3] = (T)bw.w;
    __syncthreads();
#pragma unroll
    for (int kk = 0; kk < 16; ++kk) {
      T av[4], bv2[4];
#pragma unroll
      for (int i = 0; i < 4; ++i) av[i] = As[kk][ty * 4 + i];
#pragma unroll
      for (int j = 0; j < 4; ++j) bv2[j] = Bs[kk][tx * 4 + j];
#pragma unroll
      for (int i = 0; i < 4; ++i)
#pragma unroll
        for (int j = 0; j < 4; ++j) acc[i][j] = fma_t(av[i], bv2[j], acc[i][j]);
    }
    __syncthreads();
  }
  T* Cp = C + (size_t)blockIdx.z * M * N;
#pragma unroll
  for (int i = 0; i < 4; ++i) {
    const int row = m0 + ty * 4 + i;
#pragma unroll
    for (int j = 0; j < 4; ++j) {
      const int col = n0 + tx * 4 + j;
      T v = acc[i][j];
      if (BIAS) v += (T)bias[col];
      if (RELU) v = v > (T)0 ? v : (T)0;
      Cp[(size_t)row * N + col] = v;
    }
  }
}

// split-K=2 reduction + bias (fp64, deterministic)
__global__ __launch_bounds__(256) void reduce2_bias_kernel(const double* __restrict__ part,
                                                           const float* __restrict__ bias,
                                                           double* __restrict__ out,
                                                           const int MN, const int N) {
  const int i = blockIdx.x * 256 + threadIdx.x;
  if (i < MN) out[i] = part[i] + part[MN + i] + (double)bias[i % N];
}

// ---------------------------------------------------------------------------
// K4b: pre-transpose weights so each output's weight row is contiguous.
// WqT/WkT/WvT/WoT: [4][48][48] (T[l][j][i] = W[l][i][j])
// W1T: [4][96][48], W2T: [4][48][96], embT: [512][48] (embT now unused by ar)
// ---------------------------------------------------------------------------
__global__ __launch_bounds__(256) void transpose_weights_kernel(
    const float* __restrict__ Wq, const float* __restrict__ Wk,
    const float* __restrict__ Wv, const float* __restrict__ Wo,
    const float* __restrict__ W1, const float* __restrict__ W2,
    const float* __restrict__ emb,
    float* __restrict__ WqT, float* __restrict__ WkT,
    float* __restrict__ WvT, float* __restrict__ WoT,
    float* __restrict__ W1T, float* __restrict__ W2T,
    float* __restrict__ embT) {
  const int t = blockIdx.x * 256 + threadIdx.x;  // 0 .. 98303
  if (t < 36864) {                     // Wq|Wk|Wv|Wo: 4 arrays x 4 layers x 48x48
    const int a = t / 9216, r = t - a * 9216;
    const int l = r / 2304, e = r - l * 2304;
    const int i = e / 48, j = e - i * 48;
    const float* src = a == 0 ? Wq : a == 1 ? Wk : a == 2 ? Wv : Wo;
    float* dst = a == 0 ? WqT : a == 1 ? WkT : a == 2 ? WvT : WoT;
    dst[l * 2304 + j * 48 + i] = src[l * 2304 + i * 48 + j];
  } else if (t < 55296) {              // W1 [4][48][96] -> W1T [4][96][48]
    const int t1 = t - 36864;
    const int l = t1 / 4608, e = t1 - l * 4608;
    const int i = e / 96, j = e - i * 96;
    W1T[l * 4608 + j * 48 + i] = W1[l * 4608 + i * 96 + j];
  } else if (t < 73728) {              // W2 [4][96][48] -> W2T [4][48][96]
    const int t2 = t - 55296;
    const int l = t2 / 4608, e = t2 - l * 4608;
    const int i = e / 48, j = e - i * 48;
    W2T[l * 4608 + j * 96 + i] = W2[l * 4608 + i * 48 + j];
  } else {                             // emb [48][512] -> embT [512][48]
    const int t3 = t - 73728;
    const int d = t3 / 512, e = t3 - d * 512;
    embT[e * 48 + d] = emb[d * 512 + e];
  }
}

// ---------------------------------------------------------------------------
// K5: prefill — one block per batch element (unchanged; bit-identical)
// ---------------------------------------------------------------------------
__global__ __launch_bounds__(256) void prefill_kernel(
    const double* __restrict__ toks,
    const float* __restrict__ lnq_g, const float* __restrict__ lnq_b,
    const float* __restrict__ Wq, const float* __restrict__ bq,
    const float* __restrict__ lnk_g, const float* __restrict__ lnk_b,
    const float* __restrict__ Wk, const float* __restrict__ bk,
    const float* __restrict__ lnv_g, const float* __restrict__ lnv_b,
    const float* __restrict__ Wv, const float* __restrict__ bvv,
    const float* __restrict__ Wo, const float* __restrict__ bo,
    const float* __restrict__ mln_g, const float* __restrict__ mln_b,
    const float* __restrict__ W1, const float* __restrict__ b1,
    const float* __restrict__ W2, const float* __restrict__ b2,
    double* __restrict__ kcache, double* __restrict__ vcache) {
  const int b = blockIdx.x, tid = threadIdx.x;
  __shared__ double xcur[1536], abuf[1536], qbuf[1536], kvbuf[3072];
  __shared__ double mean[32], rstd[32];
  double* kb = kvbuf;
  double* vb = kvbuf + 1536;

#pragma unroll 1
  for (int i = tid; i < 1536; i += 256) xcur[i] = toks[(size_t)b * 1536 + i];
  __syncthreads();

#pragma unroll 1
  for (int l = 0; l < 4; ++l) {
    if (tid < 32) {
      double s = 0.0, s2 = 0.0;
#pragma unroll 4
      for (int i = 0; i < 48; ++i) { const double v = xcur[tid * 48 + i]; s += v; s2 += v * v; }
      const double m = s / 48.0;
      mean[tid] = m;
      rstd[tid] = 1.0 / sqrt(s2 / 48.0 - m * m + 1e-5);
    }
    __syncthreads();
    const bool last = (l == 3);

    if (!last) {  // q projection
#pragma unroll 1
      for (int i = tid; i < 1536; i += 256) {
        const int t = i / 48, d = i % 48;
        abuf[i] = (xcur[i] - mean[t]) * rstd[t] * (double)lnq_g[l * 48 + d] + (double)lnq_b[l * 48 + d];
      }
      __syncthreads();
#pragma unroll 1
      for (int i = tid; i < 1536; i += 256) {
        const int t = i / 48, j = i % 48;
        qbuf[i] = dotW(abuf + t * 48, Wq + l * 2304 + j, 48, 48, (double)bq[l * 48 + j]);
      }
      __syncthreads();
    }
    // k projection
#pragma unroll 1
    for (int i = tid; i < 1536; i += 256) {
      const int t = i / 48, d = i % 48;
      abuf[i] = (xcur[i] - mean[t]) * rstd[t] * (double)lnk_g[l * 48 + d] + (double)lnk_b[l * 48 + d];
    }
    __syncthreads();
#pragma unroll 1
    for (int i = tid; i < 1536; i += 256) {
      const int t = i / 48, j = i % 48;
      kb[i] = dotW(abuf + t * 48, Wk + l * 2304 + j, 48, 48, (double)bk[l * 48 + j]);
    }
    __syncthreads();
    // v projection
#pragma unroll 1
    for (int i = tid; i < 1536; i += 256) {
      const int t = i / 48, d = i % 48;
      abuf[i] = (xcur[i] - mean[t]) * rstd[t] * (double)lnv_g[l * 48 + d] + (double)lnv_b[l * 48 + d];
    }
    __syncthreads();
#pragma unroll 1
    for (int i = tid; i < 1536; i += 256) {
      const int t = i / 48, j = i % 48;
      vb[i] = dotW(abuf + t * 48, Wv + l * 2304 + j, 48, 48, (double)bvv[l * 48 + j]);
    }
    __syncthreads();
    // store k,v to cache at pos t
#pragma unroll 1
    for (int i = tid; i < 1536; i += 256) {
      const int t = i / 48, j = i % 48;
      const int h = j / 6, d = j % 6;
      const size_t ci = ((((size_t)b * 4 + l) * 8 + h) * 64 + t) * 6 + d;
      kcache[ci] = kb[i];
      vcache[ci] = vb[i];
    }

    if (!last) {
      // attention: thread = (token t, head h). mask only (t=0, j=31).
      const int t = tid >> 3, h = tid & 7;
      const double* qp = qbuf + t * 48 + h * 6;
      const double q0 = qp[0], q1 = qp[1], q2 = qp[2], q3 = qp[3], q4 = qp[4], q5 = qp[5];
      double mx = -1e300;
#pragma unroll 4
      for (int j = 0; j < 32; ++j) {
        const double* kp = kb + j * 48 + h * 6;
        double sv = q0 * kp[0];
        sv = fma(q1, kp[1], sv); sv = fma(q2, kp[2], sv); sv = fma(q3, kp[3], sv);
        sv = fma(q4, kp[4], sv); sv = fma(q5, kp[5], sv);
        sv /= SCALE_;
        if (t == 0 && j == 31) sv -= 999.0;
        mx = sv > mx ? sv : mx;
      }
      double den = 0, o0 = 0, o1 = 0, o2 = 0, o3 = 0, o4 = 0, o5 = 0;
#pragma unroll 4
      for (int j = 0; j < 32; ++j) {
        const double* kp = kb + j * 48 + h * 6;
        double sv = q0 * kp[0];
        sv = fma(q1, kp[1], sv); sv = fma(q2, kp[2], sv); sv = fma(q3, kp[3], sv);
        sv = fma(q4, kp[4], sv); sv = fma(q5, kp[5], sv);
        sv /= SCALE_;
        if (t == 0 && j == 31) sv -= 999.0;
        const double e = exp_ni(sv - mx);
        den += e;
        const double* vp = vb + j * 48 + h * 6;
        o0 = fma(e, vp[0], o0); o1 = fma(e, vp[1], o1); o2 = fma(e, vp[2], o2);
        o3 = fma(e, vp[3], o3); o4 = fma(e, vp[4], o4); o5 = fma(e, vp[5], o5);
      }
      abuf[t * 48 + h * 6 + 0] = o0 / den;
      abuf[t * 48 + h * 6 + 1] = o1 / den;
      abuf[t * 48 + h * 6 + 2] = o2 / den;
      abuf[t * 48 + h * 6 + 3] = o3 / den;
      abuf[t * 48 + h * 6 + 4] = o4 / den;
      abuf[t * 48 + h * 6 + 5] = o5 / den;
      __syncthreads();
      // Wo + residual
#pragma unroll 1
      for (int i = tid; i < 1536; i += 256) {
        const int t2 = i / 48, j = i % 48;
        xcur[i] += dotW(abuf + t2 * 48, Wo + l * 2304 + j, 48, 48, (double)bo[l * 48 + j]);
      }
      __syncthreads();
      // MLP LN
      if (tid < 32) {
        double s = 0.0, s2 = 0.0;
#pragma unroll 4
        for (int i = 0; i < 48; ++i) { const double v = xcur[tid * 48 + i]; s += v; s2 += v * v; }
        const double m = s / 48.0;
        mean[tid] = m;
        rstd[tid] = 1.0 / sqrt(s2 / 48.0 - m * m + 1e-5);
      }
      __syncthreads();
#pragma unroll 1
      for (int i = tid; i < 1536; i += 256) {
        const int t2 = i / 48, d = i % 48;
        qbuf[i] = (xcur[i] - mean[t2]) * rstd[t2] * (double)mln_g[l * 48 + d] + (double)mln_b[l * 48 + d];
      }
      __syncthreads();
#pragma unroll 1
      for (int i = tid; i < 3072; i += 256) {
        const int t2 = i / 96, jj = i % 96;
        const double acc = dotW(qbuf + t2 * 48, W1 + l * 4608 + jj, 48, 96, (double)b1[l * 96 + jj]);
        kvbuf[i] = acc > 0 ? acc : 0;
      }
      __syncthreads();
#pragma unroll 1
      for (int i = tid; i < 1536; i += 256) {
        const int t2 = i / 48, j = i % 48;
        abuf[i] = dotW(kvbuf + t2 * 96, W2 + l * 4608 + j, 96, 48, (double)b2[l * 48 + j]);
      }
      __syncthreads();
#pragma unroll 1
      for (int i = tid; i < 1536; i += 256) xcur[i] = abuf[i];
      __syncthreads();
    }
  }
}

// ---------------------------------------------------------------------------
// attention phase for ar_kernel: lane (hl, rl) owns rows rl and rl+32 of its
// head; K/V in registers. Reduction code identical to the passing round-2.
// ---------------------------------------------------------------------------
__device__ __forceinline__ void attn_phase(
    const int hl, const int rl, const int p,
    const double* __restrict__ qs, double* __restrict__ os,
    const float* __restrict__ knew, const float* __restrict__ vnew,
    float (&klo)[6], float (&khi)[6], float (&vlo)[6], float (&vhi)[6]) {
  // owner lane of row p picks up the new k,v (p>=32 always -> hi half)
  if (rl == (p & 31)) {
#pragma unroll
    for (int d = 0; d < 6; ++d) { khi[d] = knew[hl * 6 + d]; vhi[d] = vnew[hl * 6 + d]; }
  }
  const double qv0 = qs[hl * 6 + 0], qv1 = qs[hl * 6 + 1], qv2 = qs[hl * 6 + 2],
               qv3 = qs[hl * 6 + 3], qv4 = qs[hl * 6 + 4], qv5 = qs[hl * 6 + 5];
  const bool has2 = (rl + 32) < p;
  double sv1 = qv0 * (double)klo[0];
  sv1 = fma(qv1, (double)klo[1], sv1); sv1 = fma(qv2, (double)klo[2], sv1);
  sv1 = fma(qv3, (double)klo[3], sv1); sv1 = fma(qv4, (double)klo[4], sv1);
  sv1 = fma(qv5, (double)klo[5], sv1);
  sv1 /= SCALE_;
  double sv2 = -1e300;
  if (has2) {
    double t2 = qv0 * (double)khi[0];
    t2 = fma(qv1, (double)khi[1], t2); t2 = fma(qv2, (double)khi[2], t2);
    t2 = fma(qv3, (double)khi[3], t2); t2 = fma(qv4, (double)khi[4], t2);
    t2 = fma(qv5, (double)khi[5], t2);
    sv2 = t2 / SCALE_;
  }
  double mx = sv1 > sv2 ? sv1 : sv2;
#pragma unroll
  for (int off = 1; off < 32; off <<= 1) { const double o2 = __shfl_xor(mx, off); mx = o2 > mx ? o2 : mx; }
  const double e1 = exp(sv1 - mx);
  const double e2 = has2 ? exp(sv2 - mx) : 0.0;
  double den = e1 + e2;
  double o[6];
#pragma unroll
  for (int d = 0; d < 6; ++d) o[d] = e1 * (double)vlo[d];
  if (has2) {
#pragma unroll
    for (int d = 0; d < 6; ++d) o[d] = fma(e2, (double)vhi[d], o[d]);
  }
#pragma unroll
  for (int off = 1; off < 32; off <<= 1) {
    den += __shfl_xor(den, off);
#pragma unroll
    for (int d = 0; d < 6; ++d) o[d] += __shfl_xor(o[d], off);
  }
  if (rl == 0) {
#pragma unroll
    for (int d = 0; d < 6; ++d) os[hl * 6 + d] = o[d] / den;
  }
}

// ---------------------------------------------------------------------------
// K6: autoregressive loop — one block (256 thr) per batch element.
//   * No global memory in the steady loop except COALESCED float4 weight
//     staging into LDS (padded rows: 52/100 floats -> conflict-optimal b128)
//     and coalesced emb-column reads in sampling.
//   * K AND V caches live in registers (lane = (head, row), rows r and r+32).
//   * All dot products keep the proven accumulation pairing -> bit-identical.
// ---------------------------------------------------------------------------
__global__ __launch_bounds__(256, 2) void ar_kernel(
    const float* __restrict__ pos_enc, const float* __restrict__ u,
    const float* __restrict__ lnq_g, const float* __restrict__ lnq_b,
    const float* __restrict__ WqT, const float* __restrict__ bq,
    const float* __restrict__ lnk_g, const float* __restrict__ lnk_b,
    const float* __restrict__ WkT, const float* __restrict__ bk,
    const float* __restrict__ lnv_g, const float* __restrict__ lnv_b,
    const float* __restrict__ WvT, const float* __restrict__ bvv,
    const float* __restrict__ WoT, const float* __restrict__ bo,
    const float* __restrict__ mln_g, const float* __restrict__ mln_b,
    const float* __restrict__ W1T, const float* __restrict__ b1,
    const float* __restrict__ W2T, const float* __restrict__ b2,
    const float* __restrict__ emb,
    const double* __restrict__ kcache, const double* __restrict__ vcache,
    float* __restrict__ out_tok) {
  const int b = blockIdx.x, tid = threadIdx.x;
  // wsh: padded staging. QKVO phase: 4 arrays x 48 rows x 52 floats (13 quads)
  //      = 9984 floats. W1W2 phase: W1 96 rows x 52 + W2 48 rows x 100 = 9792.
  __shared__ float wsh[9984];
  __shared__ float knew[48], vnew[48];
  __shared__ double xtk[48], anorm[144], qs[48], os[48], hh[96];
  __shared__ double probs[512], red[4];
  // par layout (floats):
  //    0 lnq_g |  192 lnq_b |  384 lnk_g |  576 lnk_b |  768 lnv_g |  960 lnv_b
  // 1152 mln_g | 1344 mln_b | 1536 bq | 1728 bk | 1920 bv | 2112 bo
  // 2304 b1[384] | 2688 b2[192]   -> total 2880
  __shared__ float par[2880];
  {
    const float* srcs[14] = {lnq_g, lnq_b, lnk_g, lnk_b, lnv_g, lnv_b, mln_g, mln_b,
                             bq, bk, bvv, bo, b1, b2};
    const int sz[14] = {192, 192, 192, 192, 192, 192, 192, 192, 192, 192, 192, 192, 384, 192};
    int base = 0;
#pragma unroll 1
    for (int a2 = 0; a2 < 14; ++a2) {
      for (int i = tid; i < sz[a2]; i += 256) par[base + i] = srcs[a2][i];
      base += sz[a2];
    }
  }
  // preload K,V positions 0..31 into lane registers (lane = head hl, row rl)
  const int hl = tid >> 5, rl = tid & 31;
  float klo0[6], khi0[6], vlo0[6], vhi0[6];
  float klo1[6], khi1[6], vlo1[6], vhi1[6];
  float klo2[6], khi2[6], vlo2[6], vhi2[6];
  float klo3[6], khi3[6], vlo3[6], vhi3[6];
#define PRELOAD_KV(L, KLO, KHI, VLO, VHI)                                          \
  {                                                                                \
    const size_t base0 = ((((size_t)b * 4 + (L)) * 8 + hl) * 64 + rl) * 6;         \
    _Pragma("unroll") for (int d = 0; d < 6; ++d) {                                \
      KLO[d] = (float)kcache[base0 + d];                                           \
      VLO[d] = (float)vcache[base0 + d];                                           \
      KHI[d] = 0.0f; VHI[d] = 0.0f;                                                \
    }                                                                              \
  }
  PRELOAD_KV(0, klo0, khi0, vlo0, vhi0)
  PRELOAD_KV(1, klo1, khi1, vlo1, vhi1)
  PRELOAD_KV(2, klo2, khi2, vlo2, vhi2)
  PRELOAD_KV(3, klo3, khi3, vlo3, vhi3)
#undef PRELOAD_KV
  __syncthreads();

  float4* const wsh4 = (float4*)wsh;

#pragma unroll 1
  for (int step = 0; step < 32; ++step) {
    const int p = 32 + step;
    if (tid < 48) xtk[tid] = (double)pos_enc[step * 48 + tid];
    __syncthreads();

#pragma unroll 1
    for (int l = 0; l < 4; ++l) {
      // ---- A': stage QKVO (coalesced, padded rows) + LN1 stats + 3 norms ----
      {
        const float4* s0 = (const float4*)(WqT + l * 2304);
        const float4* s1 = (const float4*)(WkT + l * 2304);
        const float4* s2 = (const float4*)(WvT + l * 2304);
        const float4* s3 = (const float4*)(WoT + l * 2304);
#pragma unroll 1
        for (int i = tid; i < 2304; i += 256) {
          const int a = i / 576, r = i - a * 576;       // r in [0,576)
          const int row = r / 12, q = r - row * 12;
          const float4 v = a == 0 ? s0[r] : a == 1 ? s1[r] : a == 2 ? s2[r] : s3[r];
          wsh4[a * 624 + row * 13 + q] = v;             // row stride 13 quads (52 f)
        }
        const double2 st = ln_stats48(xtk);
        if (tid < 144) {
          const int which = tid / 48, d = tid - which * 48;
          const float* gp = par + 384 * which;   // lnq_g / lnk_g / lnv_g
          const float* bp = gp + 192;
          anorm[tid] = (xtk[d] - st.x) * st.y * (double)gp[l * 48 + d] + (double)bp[l * 48 + d];
        }
      }
      __syncthreads();
      // ---- B: q,k,v projections from LDS rows ----
      if (tid < 144) {
        const int which = tid / 48, j = tid - which * 48;
        const float* bbp = par + 1536 + 192 * which;  // bq / bk / bv
        const double acc = dot48_row(anorm + which * 48, wsh + which * 2496 + j * 52,
                                     (double)bbp[l * 48 + j]);
        if (which == 0) {
          qs[j] = acc;
        } else if (which == 1) {
          knew[j] = (float)acc;
        } else {
          vnew[j] = (float)acc;   // FIX: j already rebased to [0,48)
        }
      }
      __syncthreads();
      // ---- C: pickup + attention (registers + shuffles only) ----
      switch (l) {
        case 0: attn_phase(hl, rl, p, qs, os, knew, vnew, klo0, khi0, vlo0, vhi0); break;
        case 1: attn_phase(hl, rl, p, qs, os, knew, vnew, klo1, khi1, vlo1, vhi1); break;
        case 2: attn_phase(hl, rl, p, qs, os, knew, vnew, klo2, khi2, vlo2, vhi2); break;
        default: attn_phase(hl, rl, p, qs, os, knew, vnew, klo3, khi3, vlo3, vhi3); break;
      }
      __syncthreads();
      // ---- D: Wo + residual ----
      if (tid < 48)
        xtk[tid] += dot48_row(os, wsh + 3 * 2496 + tid * 52, (double)par[2112 + l * 48 + tid]);
      __syncthreads();
      // ---- E: stage W1|W2 (padded) + MLP LN ----
      {
        const float4* s1q = (const float4*)(W1T + l * 4608);
        const float4* s2q = (const float4*)(W2T + l * 4608);
#pragma unroll 1
        for (int i = tid; i < 2304; i += 256) {
          if (i < 1152) {
            const int row = i / 12, q = i - row * 12;
            wsh4[row * 13 + q] = s1q[i];                // W1 rows: 52-float stride
          } else {
            const int i2 = i - 1152;
            const int row = i2 / 24, q = i2 - row * 24;
            wsh4[1248 + row * 25 + q] = s2q[i2];        // W2 rows: 100-float stride
          }
        }
        const double2 st = ln_stats48(xtk);
        if (tid < 48)
          anorm[tid] = (xtk[tid] - st.x) * st.y * (double)par[1152 + l * 48 + tid]
                       + (double)par[1344 + l * 48 + tid];
      }
      __syncthreads();
      // ---- F: MLP1 ----
      if (tid < 96) {
        const double v2 = dot48_row(anorm, wsh + tid * 52, (double)par[2304 + l * 96 + tid]);
        hh[tid] = v2 > 0 ? v2 : 0;
      }
      __syncthreads();
      // ---- G: MLP2 (no residual) ----
      if (tid < 48)
        xtk[tid] = dot96_row(hh, wsh + 4992 + tid * 100, (double)par[2688 + l * 48 + tid]);
      __syncthreads();
    }

    // ---- sampling: round-0 code (coalesced emb-column logits) ----
    {
      const double lg1 = dotN<48>(xtk, emb + tid, 512, 0.0);
      const double lg2 = dotN<48>(xtk, emb + 256 + tid, 512, 0.0);
      double mx = lg1 > lg2 ? lg1 : lg2;
#pragma unroll
      for (int off = 1; off < 64; off <<= 1) { const double o2 = __shfl_xor(mx, off); mx = o2 > mx ? o2 : mx; }
      if ((tid & 63) == 0) red[tid >> 6] = mx;
      __syncthreads();
      {
        const double m0 = red[0] > red[1] ? red[0] : red[1];
        const double m1 = red[2] > red[3] ? red[2] : red[3];
        mx = m0 > m1 ? m0 : m1;
      }
      probs[tid] = exp(lg1 - mx);
      probs[tid + 256] = exp(lg2 - mx);
      __syncthreads();
      if (tid < 64) {
        const int lane = tid;
        double loc[8], run = 0;
#pragma unroll
        for (int n2 = 0; n2 < 8; ++n2) { run += probs[lane * 8 + n2]; loc[n2] = run; }
        double incl = run;
#pragma unroll
        for (int off = 1; off < 64; off <<= 1) {
          const double t2 = __shfl_up(incl, off);
          if (lane >= off) incl += t2;
        }
        const double excl = incl - run;
        const double Ssum = __shfl(incl, 63);
        const double uu = (double)u[step * 512 + b];
        int cnt = 0;
#pragma unroll
        for (int n2 = 0; n2 < 8; ++n2) cnt += ((excl + loc[n2]) / Ssum < uu) ? 1 : 0;
#pragma unroll
        for (int off = 1; off < 64; off <<= 1) cnt += __shfl_xor(cnt, off);
        const int idx = cnt > 511 ? 511 : cnt;
        if (lane < 48) {
          const double sel = (double)emb[lane * 512 + idx];
          const double att = xtk[lane];
          out_tok[(size_t)b * 1536 + step * 48 + lane] = (float)((sel + att) - att);  // straight-through fwd
        }
      }
      __syncthreads();
    }
  }
}

// ---------------------------------------------------------------------------
// Launch
// ---------------------------------------------------------------------------
extern "C" void kernel_launch(void* const* d_in, const int* in_sizes, int n_in,
                              void* d_out, int out_size, void* d_ws, size_t ws_size,
                              hipStream_t stream) {
  const float* x      = (const float*)d_in[0];
  const float* u      = (const float*)d_in[1];
  const float* bn_g   = (const float*)d_in[2];
  const float* bn_b   = (const float*)d_in[3];
  const float* conv_w = (const float*)d_in[4];
  const float* conv_b = (const float*)d_in[5];
  const float* tk_W1  = (const float*)d_in[6];
  const float* tk_b1  = (const float*)d_in[7];
  const float* tk_W2  = (const float*)d_in[8];
  const float* tk_b2  = (const float*)d_in[9];
  const float* lnq_g  = (const float*)d_in[10];
  const float* lnq_b  = (const float*)d_in[11];
  const float* Wq     = (const float*)d_in[12];
  const float* bq     = (const float*)d_in[13];
  const float* lnk_g  = (const float*)d_in[14];
  const float* lnk_b  = (const float*)d_in[15];
  const float* Wk     = (const float*)d_in[16];
  const float* bk     = (const float*)d_in[17];
  const float* lnv_g  = (const float*)d_in[18];
  const float* lnv_b  = (const float*)d_in[19];
  const float* Wv     = (const float*)d_in[20];
  const float* bvv    = (const float*)d_in[21];
  const float* Wo     = (const float*)d_in[22];
  const float* bo     = (const float*)d_in[23];
  const float* mln_g  = (const float*)d_in[24];
  const float* mln_b  = (const float*)d_in[25];
  const float* W1     = (const float*)d_in[26];
  const float* b1     = (const float*)d_in[27];
  const float* W2     = (const float*)d_in[28];
  const float* b2     = (const float*)d_in[29];
  const float* emb    = (const float*)d_in[30];
  const float* pos    = (const float*)d_in[31];
  const float* dW1    = (const float*)d_in[32];
  const float* db1    = (const float*)d_in[33];
  const float* dW2    = (const float*)d_in[34];
  const float* db2    = (const float*)d_in[35];
  float* out = (float*)d_out;

  char* w = (char*)d_ws;
  size_t off = 0;
  auto alloc = [&](size_t bytes) {
    size_t o = off;
    off = (off + bytes + 255) & ~(size_t)255;
    return o;
  };
  const size_t o_bnp  = alloc(512 * 14 * 8);
  const size_t o_bns  = alloc(14 * 8);
  const size_t o_xf   = alloc(16777216);   // xf fp64; later reused for split-K partials (12.6MB)
  const size_t o_h    = alloc(33554432);   // h fp64; later reused for out_tok(3.1MB)+dh(6.3MB)+W^T(@16MB)
  const size_t o_toks = alloc(6291456);
  const size_t o_kc   = alloc(50331648);
  const size_t o_vc   = alloc(50331648);

  double* bnp  = (double*)(w + o_bnp);
  double* bns  = (double*)(w + o_bns);
  double* xf   = (double*)(w + o_xf);
  double* hbuf = (double*)(w + o_h);
  double* toks = (double*)(w + o_toks);
  double* kc   = (double*)(w + o_kc);
  double* vc   = (double*)(w + o_vc);
  double* part = (double*)(w + o_xf);                 // reuse (xf dead after G1)
  float*  otok = (float*)(w + o_h);                   // reuse (h dead after G2)
  float*  dh   = (float*)(w + o_h + 4194304);
  // transposed weights live in the dead tail of the h region (16MB..16.4MB;
  // otok ends at 3.1MB, dh ends at 10.5MB -> no overlap). Written after G2.
  float* WqT  = (float*)(w + o_h + 16777216);
  float* WkT  = WqT + 9216;
  float* WvT  = WkT + 9216;
  float* WoT  = WvT + 9216;
  float* W1T  = WoT + 9216;   // 18432 floats
  float* W2T  = W1T + 18432;  // 18432 floats
  float* embT = W2T + 18432;  // 24576 floats

  // 1-2: BatchNorm stats (deterministic fp64)
  bn_partial_kernel<<<512, 256, 0, stream>>>(x, bnp);
  bn_final_kernel<<<1, 64, 0, stream>>>(bnp, bn_g, bn_b, bns);
  // 3: BN-apply + conv + flatten -> xf [512,4096]
  conv_kernel<<<8192, 256, 0, stream>>>(x, conv_w, conv_b, bns, xf);
  // 4: h = relu(xf @ tk_W1 + b1)  [512,8192]  (128x64 tile fp64)
  gemm128_kernel<double, true, true><<<dim3(128, 4, 1), 256, 0, stream>>>(
      xf, tk_W1, tk_b1, hbuf, 512, 8192, 4096, 4096);
  // 5: toks = h @ tk_W2 + b2 (split-K=2 into partials, then reduce)
  gemm128_kernel<double, false, false><<<dim3(24, 4, 2), 256, 0, stream>>>(
      hbuf, tk_W2, nullptr, part, 512, 1536, 8192, 4096);
  reduce2_bias_kernel<<<3072, 256, 0, stream>>>(part, tk_b2, toks, 512 * 1536, 1536);
  // 5b: pre-transpose attention/MLP weights (hbuf now dead)
  transpose_weights_kernel<<<384, 256, 0, stream>>>(Wq, Wk, Wv, Wo, W1, W2, emb,
      WqT, WkT, WvT, WoT, W1T, W2T, embT);
  // 6: prefill (fills KV caches, positions 0..31)
  prefill_kernel<<<512, 256, 0, stream>>>(toks,
      lnq_g, lnq_b, Wq, bq, lnk_g, lnk_b, Wk, bk, lnv_g, lnv_b, Wv, bvv,
      Wo, bo, mln_g, mln_b, W1, b1, W2, b2, kc, vc);
  // 7: autoregressive loop (32 steps x 4 layers; KV in regs, staged weights)
  ar_kernel<<<512, 256, 0, stream>>>(pos, u,
      lnq_g, lnq_b, WqT, bq, lnk_g, lnk_b, WkT, bk, lnv_g, lnv_b, WvT, bvv,
      WoT, bo, mln_g, mln_b, W1T, b1, W2T, b2, emb, kc, vc, otok);
  // 8: decoder (fp32 — post-sampling, continuous path)
  gemm_kernel<float, true, true><<<dim3(48, 8, 1), 256, 0, stream>>>(
      otok, dW1, db1, dh, 512, 3072, 1536, 1536);
  gemm_kernel<float, true, false><<<dim3(28, 8, 1), 256, 0, stream>>>(
      dh, dW2, db2, out, 512, 1792, 3072, 3072);
}

// Round 6
// 4461.839 us; speedup vs baseline: 1.1852x; 1.1565x over previous
//
#include <hip/hip_runtime.h>

// ---------------------------------------------------------------------------
// Dims
// ---------------------------------------------------------------------------
// B=512 A=256 CIN=7 CC=16 D=48 H=8 DH=6 E=512 S=32 T=32 NL=4 STOT=64
// CONV_IN=4096 HID=8192 ENC=1536 DEC_HID=3072 DEC_OUT=1792
static const double SCALE_ = 6.928203230275509;  // sqrt(48)

__device__ inline float  fma_t(float a, float b, float c)  { return fmaf(a, b, c); }
__device__ inline double fma_t(double a, double b, double c){ return fma(a, b, c); }

// ---------------------------------------------------------------------------
// Helpers
// ---------------------------------------------------------------------------
// noinline dual-acc dot (prefill; pairing matches R3 exactly)
__device__ __attribute__((noinline)) double dotW(const double* a,
                                                 const float* W, int n, int ldw,
                                                 double init) {
  double a0 = init, a1 = 0.0;
#pragma unroll 2
  for (int i = 0; i < n; i += 2) {
    a0 = fma(a[i],     (double)W[i * ldw],       a0);
    a1 = fma(a[i + 1], (double)W[(i + 1) * ldw], a1);
  }
  return a0 + a1;
}

// quad-acc dot with stride (sampling; pairing i%4 -> c0..c3, proven)
template <int N, typename WP>
__device__ __forceinline__ double dotN(const double* a, WP W, int ldw, double init) {
  double c0 = init, c1 = 0.0, c2 = 0.0, c3 = 0.0;
#pragma unroll
  for (int i = 0; i < N; i += 4) {
    c0 = fma(a[i],     (double)W[i * ldw],       c0);
    c1 = fma(a[i + 1], (double)W[(i + 1) * ldw], c1);
    c2 = fma(a[i + 2], (double)W[(i + 2) * ldw], c2);
    c3 = fma(a[i + 3], (double)W[(i + 3) * ldw], c3);
  }
  return (c0 + c1) + (c2 + c3);
}

// quad-acc dots over a contiguous weight row (global; float4 reads).
// Accumulator pairing identical to dotN -> bit-identical results.
__device__ __forceinline__ double dot48_row(const double* a, const float* Wrow, double init) {
  double c0 = init, c1 = 0.0, c2 = 0.0, c3 = 0.0;
#pragma unroll
  for (int i = 0; i < 48; i += 4) {
    const float4 wv = *(const float4*)(Wrow + i);
    c0 = fma(a[i],     (double)wv.x, c0);
    c1 = fma(a[i + 1], (double)wv.y, c1);
    c2 = fma(a[i + 2], (double)wv.z, c2);
    c3 = fma(a[i + 3], (double)wv.w, c3);
  }
  return (c0 + c1) + (c2 + c3);
}

__device__ __forceinline__ double dot96_row(const double* a, const float* Wrow, double init) {
  double c0 = init, c1 = 0.0, c2 = 0.0, c3 = 0.0;
#pragma unroll
  for (int i = 0; i < 96; i += 4) {
    const float4 wv = *(const float4*)(Wrow + i);
    c0 = fma(a[i],     (double)wv.x, c0);
    c1 = fma(a[i + 1], (double)wv.y, c1);
    c2 = fma(a[i + 2], (double)wv.z, c2);
    c3 = fma(a[i + 3], (double)wv.w, c3);
  }
  return (c0 + c1) + (c2 + c3);
}

// LayerNorm stats over 48 elements (redundant per-thread; identical to prev)
__device__ __attribute__((noinline)) double2 ln_stats48(const double* x) {
  double s0 = 0, s1 = 0, q0 = 0, q1 = 0;
#pragma unroll 2
  for (int i = 0; i < 48; i += 2) {
    const double va = x[i], vb = x[i + 1];
    s0 += va; q0 = fma(va, va, q0);
    s1 += vb; q1 = fma(vb, vb, q1);
  }
  const double m = (s0 + s1) / 48.0;
  const double rs = 1.0 / sqrt((q0 + q1) / 48.0 - m * m + 1e-5);
  return make_double2(m, rs);
}

__device__ __attribute__((noinline)) double exp_ni(double x) { return exp(x); }

// ---------------------------------------------------------------------------
// K1: BatchNorm partial sums (deterministic, fp64)
// ---------------------------------------------------------------------------
__global__ __launch_bounds__(256) void bn_partial_kernel(const float* __restrict__ x,
                                                         double* __restrict__ part) {
  __shared__ double sh[256 * 14];
  const int tid = threadIdx.x;
  const int idx = blockIdx.x * 256 + tid;  // (b,a) pair, 0..131071
  const float* p = x + (size_t)idx * 7;
  for (int c = 0; c < 7; ++c) {
    double v = (double)p[c];
    sh[tid * 14 + c] = v;
    sh[tid * 14 + 7 + c] = v * v;
  }
  __syncthreads();
  if (tid < 14) {
    double acc = 0.0;
    for (int t = 0; t < 256; ++t) acc += sh[t * 14 + tid];
    part[blockIdx.x * 14 + tid] = acc;
  }
}

// K2: finalize BN stats -> per-channel scale/shift (fp64)
__global__ void bn_final_kernel(const double* __restrict__ part,
                                const float* __restrict__ g, const float* __restrict__ bb,
                                double* __restrict__ stat) {
  const int c = threadIdx.x;
  if (c < 7) {
    double s = 0.0, s2 = 0.0;
    for (int i = 0; i < 512; ++i) { s += part[i * 14 + c]; s2 += part[i * 14 + 7 + c]; }
    const double mean = s / 131072.0;
    const double var = s2 / 131072.0 - mean * mean;
    const double rstd = 1.0 / sqrt(var + 1e-5);
    const double scale = rstd * (double)g[c];
    stat[c] = scale;                          // x*scale + shift
    stat[7 + c] = (double)bb[c] - mean * scale;
  }
}

// ---------------------------------------------------------------------------
// K3: BN-apply + Conv1d(7->16,k=5,pad=2) + flatten -> xf [512, 16*256] fp64
// ---------------------------------------------------------------------------
__global__ __launch_bounds__(256) void conv_kernel(const float* __restrict__ x,
                                                   const float* __restrict__ wconv,
                                                   const float* __restrict__ cb,
                                                   const double* __restrict__ stat,
                                                   double* __restrict__ xf) {
  __shared__ double wsh[560 + 14];
  const int tid = threadIdx.x;
  for (int i = tid; i < 560; i += 256) wsh[i] = (double)wconv[i];
  for (int i = tid; i < 14; i += 256) wsh[560 + i] = stat[i];
  __syncthreads();
  const int idx = blockIdx.x * 256 + tid;    // b*4096 + o*256 + a
  const int a = idx & 255;
  const int o = (idx >> 8) & 15;
  const int b = idx >> 12;
  double acc = (double)cb[o];
  const float* xb = x + (size_t)b * (256 * 7);
  for (int k = 0; k < 5; ++k) {
    const int pos = a + k - 2;
    if (pos < 0 || pos >= 256) continue;
    const float* xp = xb + pos * 7;
    for (int ci = 0; ci < 7; ++ci) {
      const double xn = (double)xp[ci] * wsh[560 + ci] + wsh[567 + ci];
      acc = fma(xn, wsh[(o * 7 + ci) * 5 + k], acc);
    }
  }
  xf[idx] = acc;
}

// ---------------------------------------------------------------------------
// fp64 GEMM, 128x64 tile, BK=16, 256 threads, 8x4 microtile. (unchanged)
// ---------------------------------------------------------------------------
template <typename T, bool BIAS, bool RELU>
__global__ __launch_bounds__(256) void gemm128_kernel(const T* __restrict__ A,
                                                      const float* __restrict__ Bm,
                                                      const float* __restrict__ bias,
                                                      T* __restrict__ C,
                                                      const int M, const int N, const int K,
                                                      const int kc) {
  __shared__ T As[16][130];  // [k][m], pad +2
  __shared__ T Bs[16][66];   // [k][n], pad +2
  const int tid = threadIdx.x;
  const int tx = tid & 15, ty = tid >> 4;
  const int n0 = blockIdx.x * 64, m0 = blockIdx.y * 128;
  const int k0 = blockIdx.z * kc, kend = k0 + kc;
  const int ar = tid >> 1, ac = (tid & 1) * 8;   // A: 128 rows x 16 k
  const int br = tid >> 4, bc = (tid & 15) * 4;  // B: 16 k x 64 n
  const T* Ap = A + (size_t)(m0 + ar) * K;
  const float* Bp = Bm + (size_t)br * N + n0 + bc;
  T acc[8][4] = {};
  for (int k = k0; k < kend; k += 16) {
    T av8[8];
#pragma unroll
    for (int i = 0; i < 8; ++i) av8[i] = Ap[k + ac + i];
    const float4 bw = *(const float4*)(Bp + (size_t)k * N);
#pragma unroll
    for (int i = 0; i < 8; ++i) As[ac + i][ar] = av8[i];
    Bs[br][bc] = (T)bw.x; Bs[br][bc + 1] = (T)bw.y;
    Bs[br][bc + 2] = (T)bw.z; Bs[br][bc + 3] = (T)bw.w;
    __syncthreads();
#pragma unroll
    for (int kk = 0; kk < 16; ++kk) {
      T a[8], b[4];
#pragma unroll
      for (int i = 0; i < 8; ++i) a[i] = As[kk][ty * 8 + i];
#pragma unroll
      for (int j = 0; j < 4; ++j) b[j] = Bs[kk][tx * 4 + j];
#pragma unroll
      for (int i = 0; i < 8; ++i)
#pragma unroll
        for (int j = 0; j < 4; ++j) acc[i][j] = fma_t(a[i], b[j], acc[i][j]);
    }
    __syncthreads();
  }
  T* Cp = C + (size_t)blockIdx.z * M * N;
#pragma unroll
  for (int i = 0; i < 8; ++i) {
    const int row = m0 + ty * 8 + i;
#pragma unroll
    for (int j = 0; j < 4; ++j) {
      const int col = n0 + tx * 4 + j;
      T v = acc[i][j];
      if (BIAS) v += (T)bias[col];
      if (RELU) v = v > (T)0 ? v : (T)0;
      Cp[(size_t)row * N + col] = v;
    }
  }
}

// Old 64x64 fp32 GEMM (decoder)
template <typename T, bool BIAS, bool RELU>
__global__ __launch_bounds__(256) void gemm_kernel(const T* __restrict__ A,
                                                   const float* __restrict__ Bm,
                                                   const float* __restrict__ bias,
                                                   T* __restrict__ C,
                                                   const int M, const int N, const int K,
                                                   const int kc) {
  __shared__ T As[16][65];
  __shared__ T Bs[16][65];
  const int tid = threadIdx.x;
  const int tx = tid & 15, ty = tid >> 4;
  const int n0 = blockIdx.x * 64, m0 = blockIdx.y * 64;
  const int k0 = blockIdx.z * kc, kend = k0 + kc;
  const int ar = tid >> 2, ac = (tid & 3) * 4;
  const int br = tid >> 4, bc = (tid & 15) * 4;
  const T* Ap = A + (size_t)(m0 + ar) * K;
  const float* Bp = Bm + (size_t)br * N + n0 + bc;
  T acc[4][4] = {};
  for (int k = k0; k < kend; k += 16) {
    const T a0 = Ap[k + ac], a1 = Ap[k + ac + 1], a2 = Ap[k + ac + 2], a3 = Ap[k + ac + 3];
    const float4 bw = *(const float4*)(Bp + (size_t)k * N);
    As[ac][ar] = a0; As[ac + 1][ar] = a1; As[ac + 2][ar] = a2; As[ac + 3][ar] = a3;
    Bs[br][bc] = (T)bw.x; Bs[br][bc + 1] = (T)bw.y; Bs[br][bc + 2] = (T)bw.z; Bs[br][bc + 3] = (T)bw.w;
    __syncthreads();
#pragma unroll
    for (int kk = 0; kk < 16; ++kk) {
      T av[4], bv2[4];
#pragma unroll
      for (int i = 0; i < 4; ++i) av[i] = As[kk][ty * 4 + i];
#pragma unroll
      for (int j = 0; j < 4; ++j) bv2[j] = Bs[kk][tx * 4 + j];
#pragma unroll
      for (int i = 0; i < 4; ++i)
#pragma unroll
        for (int j = 0; j < 4; ++j) acc[i][j] = fma_t(av[i], bv2[j], acc[i][j]);
    }
    __syncthreads();
  }
  T* Cp = C + (size_t)blockIdx.z * M * N;
#pragma unroll
  for (int i = 0; i < 4; ++i) {
    const int row = m0 + ty * 4 + i;
#pragma unroll
    for (int j = 0; j < 4; ++j) {
      const int col = n0 + tx * 4 + j;
      T v = acc[i][j];
      if (BIAS) v += (T)bias[col];
      if (RELU) v = v > (T)0 ? v : (T)0;
      Cp[(size_t)row * N + col] = v;
    }
  }
}

// split-K=2 reduction + bias (fp64, deterministic)
__global__ __launch_bounds__(256) void reduce2_bias_kernel(const double* __restrict__ part,
                                                           const float* __restrict__ bias,
                                                           double* __restrict__ out,
                                                           const int MN, const int N) {
  const int i = blockIdx.x * 256 + threadIdx.x;
  if (i < MN) out[i] = part[i] + part[MN + i] + (double)bias[i % N];
}

// ---------------------------------------------------------------------------
// K4b: pre-transpose weights so each output's weight row is contiguous.
// WqT/WkT/WvT/WoT: [4][48][48] (T[l][j][i] = W[l][i][j])
// W1T: [4][96][48], W2T: [4][48][96], embT: [512][48] (embT unused by ar)
// ---------------------------------------------------------------------------
__global__ __launch_bounds__(256) void transpose_weights_kernel(
    const float* __restrict__ Wq, const float* __restrict__ Wk,
    const float* __restrict__ Wv, const float* __restrict__ Wo,
    const float* __restrict__ W1, const float* __restrict__ W2,
    const float* __restrict__ emb,
    float* __restrict__ WqT, float* __restrict__ WkT,
    float* __restrict__ WvT, float* __restrict__ WoT,
    float* __restrict__ W1T, float* __restrict__ W2T,
    float* __restrict__ embT) {
  const int t = blockIdx.x * 256 + threadIdx.x;  // 0 .. 98303
  if (t < 36864) {                     // Wq|Wk|Wv|Wo: 4 arrays x 4 layers x 48x48
    const int a = t / 9216, r = t - a * 9216;
    const int l = r / 2304, e = r - l * 2304;
    const int i = e / 48, j = e - i * 48;
    const float* src = a == 0 ? Wq : a == 1 ? Wk : a == 2 ? Wv : Wo;
    float* dst = a == 0 ? WqT : a == 1 ? WkT : a == 2 ? WvT : WoT;
    dst[l * 2304 + j * 48 + i] = src[l * 2304 + i * 48 + j];
  } else if (t < 55296) {              // W1 [4][48][96] -> W1T [4][96][48]
    const int t1 = t - 36864;
    const int l = t1 / 4608, e = t1 - l * 4608;
    const int i = e / 96, j = e - i * 96;
    W1T[l * 4608 + j * 48 + i] = W1[l * 4608 + i * 96 + j];
  } else if (t < 73728) {              // W2 [4][96][48] -> W2T [4][48][96]
    const int t2 = t - 55296;
    const int l = t2 / 4608, e = t2 - l * 4608;
    const int i = e / 48, j = e - i * 48;
    W2T[l * 4608 + j * 96 + i] = W2[l * 4608 + i * 48 + j];
  } else {                             // emb [48][512] -> embT [512][48]
    const int t3 = t - 73728;
    const int d = t3 / 512, e = t3 - d * 512;
    embT[e * 48 + d] = emb[d * 512 + e];
  }
}

// ---------------------------------------------------------------------------
// K5: prefill — one block per batch element. Math identical to the passing
// version; K/V caches stored as fp32 [B][4][8][32][6] (same values the old
// ar preload produced via (float) casts).
// ---------------------------------------------------------------------------
__global__ __launch_bounds__(256) void prefill_kernel(
    const double* __restrict__ toks,
    const float* __restrict__ lnq_g, const float* __restrict__ lnq_b,
    const float* __restrict__ Wq, const float* __restrict__ bq,
    const float* __restrict__ lnk_g, const float* __restrict__ lnk_b,
    const float* __restrict__ Wk, const float* __restrict__ bk,
    const float* __restrict__ lnv_g, const float* __restrict__ lnv_b,
    const float* __restrict__ Wv, const float* __restrict__ bvv,
    const float* __restrict__ Wo, const float* __restrict__ bo,
    const float* __restrict__ mln_g, const float* __restrict__ mln_b,
    const float* __restrict__ W1, const float* __restrict__ b1,
    const float* __restrict__ W2, const float* __restrict__ b2,
    float* __restrict__ kc32, float* __restrict__ vc32) {
  const int b = blockIdx.x, tid = threadIdx.x;
  __shared__ double xcur[1536], abuf[1536], qbuf[1536], kvbuf[3072];
  __shared__ double mean[32], rstd[32];
  double* kb = kvbuf;
  double* vb = kvbuf + 1536;

#pragma unroll 1
  for (int i = tid; i < 1536; i += 256) xcur[i] = toks[(size_t)b * 1536 + i];
  __syncthreads();

#pragma unroll 1
  for (int l = 0; l < 4; ++l) {
    if (tid < 32) {
      double s = 0.0, s2 = 0.0;
#pragma unroll 4
      for (int i = 0; i < 48; ++i) { const double v = xcur[tid * 48 + i]; s += v; s2 += v * v; }
      const double m = s / 48.0;
      mean[tid] = m;
      rstd[tid] = 1.0 / sqrt(s2 / 48.0 - m * m + 1e-5);
    }
    __syncthreads();
    const bool last = (l == 3);

    if (!last) {  // q projection
#pragma unroll 1
      for (int i = tid; i < 1536; i += 256) {
        const int t = i / 48, d = i % 48;
        abuf[i] = (xcur[i] - mean[t]) * rstd[t] * (double)lnq_g[l * 48 + d] + (double)lnq_b[l * 48 + d];
      }
      __syncthreads();
#pragma unroll 1
      for (int i = tid; i < 1536; i += 256) {
        const int t = i / 48, j = i % 48;
        qbuf[i] = dotW(abuf + t * 48, Wq + l * 2304 + j, 48, 48, (double)bq[l * 48 + j]);
      }
      __syncthreads();
    }
    // k projection
#pragma unroll 1
    for (int i = tid; i < 1536; i += 256) {
      const int t = i / 48, d = i % 48;
      abuf[i] = (xcur[i] - mean[t]) * rstd[t] * (double)lnk_g[l * 48 + d] + (double)lnk_b[l * 48 + d];
    }
    __syncthreads();
#pragma unroll 1
    for (int i = tid; i < 1536; i += 256) {
      const int t = i / 48, j = i % 48;
      kb[i] = dotW(abuf + t * 48, Wk + l * 2304 + j, 48, 48, (double)bk[l * 48 + j]);
    }
    __syncthreads();
    // v projection
#pragma unroll 1
    for (int i = tid; i < 1536; i += 256) {
      const int t = i / 48, d = i % 48;
      abuf[i] = (xcur[i] - mean[t]) * rstd[t] * (double)lnv_g[l * 48 + d] + (double)lnv_b[l * 48 + d];
    }
    __syncthreads();
#pragma unroll 1
    for (int i = tid; i < 1536; i += 256) {
      const int t = i / 48, j = i % 48;
      vb[i] = dotW(abuf + t * 48, Wv + l * 2304 + j, 48, 48, (double)bvv[l * 48 + j]);
    }
    __syncthreads();
    // store k,v (fp32) to cache at pos t: [B][4][8][32][6]
#pragma unroll 1
    for (int i = tid; i < 1536; i += 256) {
      const int t = i / 48, j = i % 48;
      const int h = j / 6, d = j % 6;
      const size_t ci = ((((size_t)b * 4 + l) * 8 + h) * 32 + t) * 6 + d;
      kc32[ci] = (float)kb[i];
      vc32[ci] = (float)vb[i];
    }

    if (!last) {
      // attention: thread = (token t, head h). mask only (t=0, j=31).
      const int t = tid >> 3, h = tid & 7;
      const double* qp = qbuf + t * 48 + h * 6;
      const double q0 = qp[0], q1 = qp[1], q2 = qp[2], q3 = qp[3], q4 = qp[4], q5 = qp[5];
      double mx = -1e300;
#pragma unroll 4
      for (int j = 0; j < 32; ++j) {
        const double* kp = kb + j * 48 + h * 6;
        double sv = q0 * kp[0];
        sv = fma(q1, kp[1], sv); sv = fma(q2, kp[2], sv); sv = fma(q3, kp[3], sv);
        sv = fma(q4, kp[4], sv); sv = fma(q5, kp[5], sv);
        sv /= SCALE_;
        if (t == 0 && j == 31) sv -= 999.0;
        mx = sv > mx ? sv : mx;
      }
      double den = 0, o0 = 0, o1 = 0, o2 = 0, o3 = 0, o4 = 0, o5 = 0;
#pragma unroll 4
      for (int j = 0; j < 32; ++j) {
        const double* kp = kb + j * 48 + h * 6;
        double sv = q0 * kp[0];
        sv = fma(q1, kp[1], sv); sv = fma(q2, kp[2], sv); sv = fma(q3, kp[3], sv);
        sv = fma(q4, kp[4], sv); sv = fma(q5, kp[5], sv);
        sv /= SCALE_;
        if (t == 0 && j == 31) sv -= 999.0;
        const double e = exp_ni(sv - mx);
        den += e;
        const double* vp = vb + j * 48 + h * 6;
        o0 = fma(e, vp[0], o0); o1 = fma(e, vp[1], o1); o2 = fma(e, vp[2], o2);
        o3 = fma(e, vp[3], o3); o4 = fma(e, vp[4], o4); o5 = fma(e, vp[5], o5);
      }
      abuf[t * 48 + h * 6 + 0] = o0 / den;
      abuf[t * 48 + h * 6 + 1] = o1 / den;
      abuf[t * 48 + h * 6 + 2] = o2 / den;
      abuf[t * 48 + h * 6 + 3] = o3 / den;
      abuf[t * 48 + h * 6 + 4] = o4 / den;
      abuf[t * 48 + h * 6 + 5] = o5 / den;
      __syncthreads();
      // Wo + residual
#pragma unroll 1
      for (int i = tid; i < 1536; i += 256) {
        const int t2 = i / 48, j = i % 48;
        xcur[i] += dotW(abuf + t2 * 48, Wo + l * 2304 + j, 48, 48, (double)bo[l * 48 + j]);
      }
      __syncthreads();
      // MLP LN
      if (tid < 32) {
        double s = 0.0, s2 = 0.0;
#pragma unroll 4
        for (int i = 0; i < 48; ++i) { const double v = xcur[tid * 48 + i]; s += v; s2 += v * v; }
        const double m = s / 48.0;
        mean[tid] = m;
        rstd[tid] = 1.0 / sqrt(s2 / 48.0 - m * m + 1e-5);
      }
      __syncthreads();
#pragma unroll 1
      for (int i = tid; i < 1536; i += 256) {
        const int t2 = i / 48, d = i % 48;
        qbuf[i] = (xcur[i] - mean[t2]) * rstd[t2] * (double)mln_g[l * 48 + d] + (double)mln_b[l * 48 + d];
      }
      __syncthreads();
#pragma unroll 1
      for (int i = tid; i < 3072; i += 256) {
        const int t2 = i / 96, jj = i % 96;
        const double acc = dotW(qbuf + t2 * 48, W1 + l * 4608 + jj, 48, 96, (double)b1[l * 96 + jj]);
        kvbuf[i] = acc > 0 ? acc : 0;
      }
      __syncthreads();
#pragma unroll 1
      for (int i = tid; i < 1536; i += 256) {
        const int t2 = i / 48, j = i % 48;
        abuf[i] = dotW(kvbuf + t2 * 96, W2 + l * 4608 + j, 96, 48, (double)b2[l * 48 + j]);
      }
      __syncthreads();
#pragma unroll 1
      for (int i = tid; i < 1536; i += 256) xcur[i] = abuf[i];
      __syncthreads();
    }
  }
}

// ---------------------------------------------------------------------------
// K6: autoregressive loop — one block (256 thr) per batch element.
//   * NO persistent per-lane arrays -> no register spills (the round-2/4 bug:
//     96 "register" KV floats spilled to scratch = ~1.6 GB hidden traffic).
//   * K/V rows 0..31: global fp32 (prefill output, read-only -> coherent).
//     K/V rows 32..63: LDS (written by this block, barrier-ordered).
//   * Weights: direct global reads of pre-transposed contiguous rows
//     (295 KB total -> L2-resident per XCD).
//   * All dot products keep the proven accumulation pairing -> bit-identical.
// ---------------------------------------------------------------------------
__global__ __launch_bounds__(256, 2) void ar_kernel(
    const float* __restrict__ pos_enc, const float* __restrict__ u,
    const float* __restrict__ lnq_g, const float* __restrict__ lnq_b,
    const float* __restrict__ WqT, const float* __restrict__ bq,
    const float* __restrict__ lnk_g, const float* __restrict__ lnk_b,
    const float* __restrict__ WkT, const float* __restrict__ bk,
    const float* __restrict__ lnv_g, const float* __restrict__ lnv_b,
    const float* __restrict__ WvT, const float* __restrict__ bvv,
    const float* __restrict__ WoT, const float* __restrict__ bo,
    const float* __restrict__ mln_g, const float* __restrict__ mln_b,
    const float* __restrict__ W1T, const float* __restrict__ b1,
    const float* __restrict__ W2T, const float* __restrict__ b2,
    const float* __restrict__ emb,
    const float* __restrict__ kc32, const float* __restrict__ vc32,
    float* __restrict__ out_tok) {
  const int b = blockIdx.x, tid = threadIdx.x;
  // New-row KV caches (positions 32..63), pad 7 -> conflict-free reads.
  __shared__ float knew[4][8][32][7];  // 28672 B
  __shared__ float vnew[4][8][32][7];  // 28672 B
  __shared__ double xtk[48], anorm[144], qs[48], os[48], hh[96];
  __shared__ double probs[512], red[4];
  // par layout (floats):
  //    0 lnq_g |  192 lnq_b |  384 lnk_g |  576 lnk_b |  768 lnv_g |  960 lnv_b
  // 1152 mln_g | 1344 mln_b | 1536 bq | 1728 bk | 1920 bv | 2112 bo
  // 2304 b1[384] | 2688 b2[192]   -> total 2880
  __shared__ float par[2880];
  {
    const float* srcs[14] = {lnq_g, lnq_b, lnk_g, lnk_b, lnv_g, lnv_b, mln_g, mln_b,
                             bq, bk, bvv, bo, b1, b2};
    const int sz[14] = {192, 192, 192, 192, 192, 192, 192, 192, 192, 192, 192, 192, 384, 192};
    int base = 0;
#pragma unroll 1
    for (int a2 = 0; a2 < 14; ++a2) {
      for (int i = tid; i < sz[a2]; i += 256) par[base + i] = srcs[a2][i];
      base += sz[a2];
    }
  }
  __syncthreads();

  const int hl = tid >> 5, rl = tid & 31;

#pragma unroll 1
  for (int step = 0; step < 32; ++step) {
    const int p = 32 + step;
    if (tid < 48) xtk[tid] = (double)pos_enc[step * 48 + tid];
    __syncthreads();

#pragma unroll 1
    for (int l = 0; l < 4; ++l) {
      // ---- A: LN1 (redundant stats) + 3 norms (144 outputs) ----
      {
        const double2 st = ln_stats48(xtk);
        if (tid < 144) {
          const int which = tid / 48, d = tid - which * 48;
          const float* gp = par + 384 * which;   // lnq_g / lnk_g / lnv_g
          const float* bp = gp + 192;
          anorm[tid] = (xtk[d] - st.x) * st.y * (double)gp[l * 48 + d] + (double)bp[l * 48 + d];
        }
      }
      __syncthreads();
      // ---- B: q,k,v projections; direct global weight rows ----
      if (tid < 144) {
        const int which = tid / 48, j = tid - which * 48;
        const float* WT = which == 0 ? WqT : which == 1 ? WkT : WvT;
        const float* bbp = par + 1536 + 192 * which;  // bq / bk / bv
        const double acc = dot48_row(anorm + which * 48, WT + l * 2304 + j * 48,
                                     (double)bbp[l * 48 + j]);
        if (which == 0) {
          qs[j] = acc;
        } else {
          const int h2 = j / 6, d2 = j - h2 * 6;
          if (which == 1) knew[l][h2][step][d2] = (float)acc;
          else            vnew[l][h2][step][d2] = (float)acc;
        }
      }
      __syncthreads();
      // ---- C: attention over [0,p): 32 lanes per head, rows rl and rl+32 ----
      {
        const size_t gb = (((size_t)b * 4 + l) * 8 + hl) * 192 + rl * 6;
        const float* kg = kc32 + gb;   // row rl (prefill region, always valid)
        const float* vg = vc32 + gb;
        const double qv0 = qs[hl * 6 + 0], qv1 = qs[hl * 6 + 1], qv2 = qs[hl * 6 + 2],
                     qv3 = qs[hl * 6 + 3], qv4 = qs[hl * 6 + 4], qv5 = qs[hl * 6 + 5];
        const bool has2 = rl < step;   // (rl+32) < p
        double sv1 = qv0 * (double)kg[0];
        sv1 = fma(qv1, (double)kg[1], sv1); sv1 = fma(qv2, (double)kg[2], sv1);
        sv1 = fma(qv3, (double)kg[3], sv1); sv1 = fma(qv4, (double)kg[4], sv1);
        sv1 = fma(qv5, (double)kg[5], sv1);
        sv1 /= SCALE_;
        double sv2 = -1e300;
        if (has2) {
          const float* kh = &knew[l][hl][rl][0];
          double t2 = qv0 * (double)kh[0];
          t2 = fma(qv1, (double)kh[1], t2); t2 = fma(qv2, (double)kh[2], t2);
          t2 = fma(qv3, (double)kh[3], t2); t2 = fma(qv4, (double)kh[4], t2);
          t2 = fma(qv5, (double)kh[5], t2);
          sv2 = t2 / SCALE_;
        }
        double mx = sv1 > sv2 ? sv1 : sv2;
#pragma unroll
        for (int off = 1; off < 32; off <<= 1) { const double o2 = __shfl_xor(mx, off); mx = o2 > mx ? o2 : mx; }
        const double e1 = exp(sv1 - mx);
        const double e2 = has2 ? exp(sv2 - mx) : 0.0;
        double den = e1 + e2;
        double o[6];
#pragma unroll
        for (int d = 0; d < 6; ++d) o[d] = e1 * (double)vg[d];
        if (has2) {
          const float* vh = &vnew[l][hl][rl][0];
#pragma unroll
          for (int d = 0; d < 6; ++d) o[d] = fma(e2, (double)vh[d], o[d]);
        }
#pragma unroll
        for (int off = 1; off < 32; off <<= 1) {
          den += __shfl_xor(den, off);
#pragma unroll
          for (int d = 0; d < 6; ++d) o[d] += __shfl_xor(o[d], off);
        }
        if (rl == 0) {
#pragma unroll
          for (int d = 0; d < 6; ++d) os[hl * 6 + d] = o[d] / den;
        }
      }
      __syncthreads();
      // ---- D: Wo + residual (direct global rows) ----
      if (tid < 48)
        xtk[tid] += dot48_row(os, WoT + l * 2304 + tid * 48, (double)par[2112 + l * 48 + tid]);
      __syncthreads();
      // ---- E: MLP LN ----
      {
        const double2 st = ln_stats48(xtk);
        if (tid < 48)
          anorm[tid] = (xtk[tid] - st.x) * st.y * (double)par[1152 + l * 48 + tid]
                       + (double)par[1344 + l * 48 + tid];
      }
      __syncthreads();
      // ---- F: MLP1 (direct global rows) ----
      if (tid < 96) {
        const double v2 = dot48_row(anorm, W1T + l * 4608 + tid * 48, (double)par[2304 + l * 96 + tid]);
        hh[tid] = v2 > 0 ? v2 : 0;
      }
      __syncthreads();
      // ---- G: MLP2 (no residual; direct global rows) ----
      if (tid < 48)
        xtk[tid] = dot96_row(hh, W2T + l * 4608 + tid * 96, (double)par[2688 + l * 48 + tid]);
      __syncthreads();
    }

    // ---- sampling: proven code (coalesced emb-column logits) ----
    {
      const double lg1 = dotN<48>(xtk, emb + tid, 512, 0.0);
      const double lg2 = dotN<48>(xtk, emb + 256 + tid, 512, 0.0);
      double mx = lg1 > lg2 ? lg1 : lg2;
#pragma unroll
      for (int off = 1; off < 64; off <<= 1) { const double o2 = __shfl_xor(mx, off); mx = o2 > mx ? o2 : mx; }
      if ((tid & 63) == 0) red[tid >> 6] = mx;
      __syncthreads();
      {
        const double m0 = red[0] > red[1] ? red[0] : red[1];
        const double m1 = red[2] > red[3] ? red[2] : red[3];
        mx = m0 > m1 ? m0 : m1;
      }
      probs[tid] = exp(lg1 - mx);
      probs[tid + 256] = exp(lg2 - mx);
      __syncthreads();
      if (tid < 64) {
        const int lane = tid;
        double loc[8], run = 0;
#pragma unroll
        for (int n2 = 0; n2 < 8; ++n2) { run += probs[lane * 8 + n2]; loc[n2] = run; }
        double incl = run;
#pragma unroll
        for (int off = 1; off < 64; off <<= 1) {
          const double t2 = __shfl_up(incl, off);
          if (lane >= off) incl += t2;
        }
        const double excl = incl - run;
        const double Ssum = __shfl(incl, 63);
        const double uu = (double)u[step * 512 + b];
        int cnt = 0;
#pragma unroll
        for (int n2 = 0; n2 < 8; ++n2) cnt += ((excl + loc[n2]) / Ssum < uu) ? 1 : 0;
#pragma unroll
        for (int off = 1; off < 64; off <<= 1) cnt += __shfl_xor(cnt, off);
        const int idx = cnt > 511 ? 511 : cnt;
        if (lane < 48) {
          const double sel = (double)emb[lane * 512 + idx];
          const double att = xtk[lane];
          out_tok[(size_t)b * 1536 + step * 48 + lane] = (float)((sel + att) - att);  // straight-through fwd
        }
      }
      __syncthreads();
    }
  }
}

// ---------------------------------------------------------------------------
// Launch
// ---------------------------------------------------------------------------
extern "C" void kernel_launch(void* const* d_in, const int* in_sizes, int n_in,
                              void* d_out, int out_size, void* d_ws, size_t ws_size,
                              hipStream_t stream) {
  const float* x      = (const float*)d_in[0];
  const float* u      = (const float*)d_in[1];
  const float* bn_g   = (const float*)d_in[2];
  const float* bn_b   = (const float*)d_in[3];
  const float* conv_w = (const float*)d_in[4];
  const float* conv_b = (const float*)d_in[5];
  const float* tk_W1  = (const float*)d_in[6];
  const float* tk_b1  = (const float*)d_in[7];
  const float* tk_W2  = (const float*)d_in[8];
  const float* tk_b2  = (const float*)d_in[9];
  const float* lnq_g  = (const float*)d_in[10];
  const float* lnq_b  = (const float*)d_in[11];
  const float* Wq     = (const float*)d_in[12];
  const float* bq     = (const float*)d_in[13];
  const float* lnk_g  = (const float*)d_in[14];
  const float* lnk_b  = (const float*)d_in[15];
  const float* Wk     = (const float*)d_in[16];
  const float* bk     = (const float*)d_in[17];
  const float* lnv_g  = (const float*)d_in[18];
  const float* lnv_b  = (const float*)d_in[19];
  const float* Wv     = (const float*)d_in[20];
  const float* bvv    = (const float*)d_in[21];
  const float* Wo     = (const float*)d_in[22];
  const float* bo     = (const float*)d_in[23];
  const float* mln_g  = (const float*)d_in[24];
  const float* mln_b  = (const float*)d_in[25];
  const float* W1     = (const float*)d_in[26];
  const float* b1     = (const float*)d_in[27];
  const float* W2     = (const float*)d_in[28];
  const float* b2     = (const float*)d_in[29];
  const float* emb    = (const float*)d_in[30];
  const float* pos    = (const float*)d_in[31];
  const float* dW1    = (const float*)d_in[32];
  const float* db1    = (const float*)d_in[33];
  const float* dW2    = (const float*)d_in[34];
  const float* db2    = (const float*)d_in[35];
  float* out = (float*)d_out;

  char* w = (char*)d_ws;
  size_t off = 0;
  auto alloc = [&](size_t bytes) {
    size_t o = off;
    off = (off + bytes + 255) & ~(size_t)255;
    return o;
  };
  const size_t o_bnp  = alloc(512 * 14 * 8);
  const size_t o_bns  = alloc(14 * 8);
  const size_t o_xf   = alloc(16777216);   // xf fp64; later reused for split-K partials (12.6MB)
  const size_t o_h    = alloc(33554432);   // h fp64; later reused for out_tok(3.1MB)+dh(6.3MB)+W^T(@16MB)
  const size_t o_toks = alloc(6291456);
  const size_t o_kc   = alloc(12582912);   // kc32 fp32 [512][4][8][32][6] = 12.58MB (R5 bug: was half)
  const size_t o_vc   = alloc(12582912);   // vc32 fp32

  double* bnp  = (double*)(w + o_bnp);
  double* bns  = (double*)(w + o_bns);
  double* xf   = (double*)(w + o_xf);
  double* hbuf = (double*)(w + o_h);
  double* toks = (double*)(w + o_toks);
  float*  kc32 = (float*)(w + o_kc);
  float*  vc32 = (float*)(w + o_vc);
  double* part = (double*)(w + o_xf);                 // reuse (xf dead after G1)
  float*  otok = (float*)(w + o_h);                   // reuse (h dead after G2)
  float*  dh   = (float*)(w + o_h + 4194304);
  // transposed weights live in the dead tail of the h region (16MB..16.4MB;
  // otok ends at 3.1MB, dh ends at 10.5MB -> no overlap). Written after G2.
  float* WqT  = (float*)(w + o_h + 16777216);
  float* WkT  = WqT + 9216;
  float* WvT  = WkT + 9216;
  float* WoT  = WvT + 9216;
  float* W1T  = WoT + 9216;   // 18432 floats
  float* W2T  = W1T + 18432;  // 18432 floats
  float* embT = W2T + 18432;  // 24576 floats

  // 1-2: BatchNorm stats (deterministic fp64)
  bn_partial_kernel<<<512, 256, 0, stream>>>(x, bnp);
  bn_final_kernel<<<1, 64, 0, stream>>>(bnp, bn_g, bn_b, bns);
  // 3: BN-apply + conv + flatten -> xf [512,4096]
  conv_kernel<<<8192, 256, 0, stream>>>(x, conv_w, conv_b, bns, xf);
  // 4: h = relu(xf @ tk_W1 + b1)  [512,8192]  (128x64 tile fp64)
  gemm128_kernel<double, true, true><<<dim3(128, 4, 1), 256, 0, stream>>>(
      xf, tk_W1, tk_b1, hbuf, 512, 8192, 4096, 4096);
  // 5: toks = h @ tk_W2 + b2 (split-K=2 into partials, then reduce)
  gemm128_kernel<double, false, false><<<dim3(24, 4, 2), 256, 0, stream>>>(
      hbuf, tk_W2, nullptr, part, 512, 1536, 8192, 4096);
  reduce2_bias_kernel<<<3072, 256, 0, stream>>>(part, tk_b2, toks, 512 * 1536, 1536);
  // 5b: pre-transpose attention/MLP weights (hbuf now dead)
  transpose_weights_kernel<<<384, 256, 0, stream>>>(Wq, Wk, Wv, Wo, W1, W2, emb,
      WqT, WkT, WvT, WoT, W1T, W2T, embT);
  // 6: prefill (fills fp32 KV caches, positions 0..31)
  prefill_kernel<<<512, 256, 0, stream>>>(toks,
      lnq_g, lnq_b, Wq, bq, lnk_g, lnk_b, Wk, bk, lnv_g, lnv_b, Wv, bvv,
      Wo, bo, mln_g, mln_b, W1, b1, W2, b2, kc32, vc32);
  // 7: autoregressive loop (32 steps x 4 layers; KV global-fp32 + LDS new rows)
  ar_kernel<<<512, 256, 0, stream>>>(pos, u,
      lnq_g, lnq_b, WqT, bq, lnk_g, lnk_b, WkT, bk, lnv_g, lnv_b, WvT, bvv,
      WoT, bo, mln_g, mln_b, W1T, b1, W2T, b2, emb, kc32, vc32, otok);
  // 8: decoder (fp32 — post-sampling, continuous path)
  gemm_kernel<float, true, true><<<dim3(48, 8, 1), 256, 0, stream>>>(
      otok, dW1, db1, dh, 512, 3072, 1536, 1536);
  gemm_kernel<float, true, false><<<dim3(28, 8, 1), 256, 0, stream>>>(
      dh, dW2, db2, out, 512, 1792, 3072, 3072);
}